// Round 9
// baseline (274.392 us; speedup 1.0000x reference)
//
#include <hip/hip_runtime.h>
#include <math.h>

typedef float f32x4 __attribute__((ext_vector_type(4)));
typedef short s16x8 __attribute__((ext_vector_type(8)));

__device__ __forceinline__ unsigned short f2bf(float f) {
    unsigned u = __builtin_bit_cast(unsigned, f);
    u += 0x7fffu + ((u >> 16) & 1u);
    return (unsigned short)(u >> 16);
}

// ---------------- weight packing ----------------
// B-frag order: frag (kt,nt): lane l elem j holds W[n=16nt+(l&15)][k=32kt+8*(l>>4)+j]
#define PACK_TOT 36864

__global__ __launch_bounds__(256) void pack_weights_k(
    const float* __restrict__ w0, const float* __restrict__ w1,
    const float* __restrict__ w2, const float* __restrict__ w3,
    const float* __restrict__ wv, unsigned short* __restrict__ dst)
{
    int idx = blockIdx.x * 256 + threadIdx.x;
    if (idx >= PACK_TOT) return;
    const float* W; int inF, ntiles, off;
    if (idx < 3072)       { W = w0; inF = 8;  ntiles = 6; off = 0; }
    else if (idx < 12288) { W = w1; inF = 96; ntiles = 6; off = 3072; }
    else if (idx < 21504) { W = w2; inF = 96; ntiles = 6; off = 12288; }
    else if (idx < 30720) { W = w3; inF = 96; ntiles = 6; off = 21504; }
    else                  { W = wv; inF = 96; ntiles = 4; off = 30720; }
    int r  = idx - off;
    int fi = r >> 9;
    int wi = r & 511;
    int l = wi >> 3, j = wi & 7;
    int kt = fi / ntiles, nt = fi - kt * ntiles;
    int n = nt * 16 + (l & 15);
    int k = kt * 32 + ((l >> 4) << 3) + j;
    float v = (k < inF) ? W[n * inF + k] : 0.0f;
    dst[idx] = f2bf(v);
}

// ---------------- CSR build ----------------
__global__ __launch_bounds__(256) void hist_k(const int* __restrict__ src,
                                              int* __restrict__ counts, int E)
{
    int e = blockIdx.x * 256 + threadIdx.x;
    if (e < E) atomicAdd(&counts[src[e]], 1);
}

__global__ __launch_bounds__(256) void scan1_k(const int* __restrict__ counts,
                                               int* __restrict__ cursor,
                                               int* __restrict__ bsum, int N)
{
    __shared__ int wsum_s[4];
    int b = blockIdx.x, t = threadIdx.x, lane = t & 63, wid = t >> 6;
    int i0 = b * 2048 + t * 8;
    int v[8]; int s = 0;
    #pragma unroll
    for (int j = 0; j < 8; j++) { int i = i0 + j; v[j] = (i < N) ? counts[i] : 0; s += v[j]; }
    int inc = s;
    #pragma unroll
    for (int d = 1; d < 64; d <<= 1) { int o = __shfl_up(inc, d, 64); if (lane >= d) inc += o; }
    if (lane == 63) wsum_s[wid] = inc;
    __syncthreads();
    int wb = 0;
    for (int k = 0; k < wid; k++) wb += wsum_s[k];
    int run = wb + inc - s;
    #pragma unroll
    for (int j = 0; j < 8; j++) { int i = i0 + j; if (i < N) cursor[i] = run; run += v[j]; }
    if (t == 255) bsum[b] = wb + inc;
}

__global__ __launch_bounds__(64) void scan2_k(int* __restrict__ bsum, int nb)
{
    int lane = threadIdx.x;
    int v = (lane < nb) ? bsum[lane] : 0;
    int inc = v;
    #pragma unroll
    for (int d = 1; d < 64; d <<= 1) { int o = __shfl_up(inc, d, 64); if (lane >= d) inc += o; }
    if (lane < nb) bsum[lane] = inc - v;
}

__global__ __launch_bounds__(256) void scatter_k(const int* __restrict__ src,
                                                 const float* __restrict__ r_ij,
                                                 const int* __restrict__ bsum,
                                                 int* __restrict__ cursor,
                                                 int* __restrict__ order,
                                                 int* __restrict__ srcs,
                                                 float4* __restrict__ rsrt,
                                                 int use_rsrt, int E)
{
    int e = blockIdx.x * 256 + threadIdx.x;
    if (e < E) {
        int s = src[e];
        int p = bsum[s >> 11] + atomicAdd(&cursor[s], 1);
        if (use_rsrt) {
            rsrt[p] = make_float4(r_ij[3*e], r_ij[3*e+1], r_ij[3*e+2], __int_as_float(s));
        } else {
            order[p] = e;
            srcs[p] = s;
        }
    }
}

// ---------------- fused edge kernel ----------------
// r7-proven structure + {bias in MFMA C-init, leaky=fmax(x,0.1x), wv push-down}.
// NO v_cvt_pk asm (bisection: prime NaN suspect from r4/5/6/8).
// wv push-down: waves 1..3 compute S_c = (I.rv_c)@rad (per 16-segment tile),
// stash S_c in A-frag order (wave-private), then Ov = S_c @ wv^T.
// Deletes vrad GEMM + 16KB vfrag -> LDS ~35.7KB -> 4 blocks/CU.
__global__ __launch_bounds__(256, 4) void edge_kernel(
    const float* __restrict__ r_ij,
    const int* __restrict__ order, const int* __restrict__ srcs,
    const float4* __restrict__ rsrt, int use_rsrt,
    const unsigned short* __restrict__ wp,
    const float* __restrict__ b0, const float* __restrict__ b1, const float* __restrict__ b2,
    float* __restrict__ A_a, float* __restrict__ Ov, int E)
{
    // [0..13312): row-major MLP buffer (stride 104, cols 96..103 = enc)
    // after SYNC2 overlay: [0..12288) = 24 rad B-frags (512 u16 each)
    // [12288..16896): per-wave S_c A-frag scratch for waves 1..3
    __shared__ unsigned short h_s[16896];
    __shared__ unsigned short rvb_s[3 * 128];      // bf16 rv, [c][row]
    __shared__ unsigned char  segid_s[128];
    __shared__ int  segnode_s[128];
    __shared__ int  src_s[128];
    __shared__ int  nseg_s;

    const int tid = threadIdx.x;
    const int w  = tid >> 6;
    const int l  = tid & 63;
    const int e0 = blockIdx.x * 128;
    const int lr = l & 15;
    const int lg = l >> 4;
    const int mbase = w * 32;

    // ---- stage per-edge scalars (coalesced float4 fast path)
    if (l < 32) {
        const int ml = mbase + l;
        const int pos = e0 + ml;
        float x = 0.f, y = 0.f, z = 0.f; int s = -1;
        if (pos < E) {
            if (use_rsrt) {
                float4 v4 = rsrt[pos];
                x = v4.x; y = v4.y; z = v4.z; s = __float_as_int(v4.w);
            } else {
                int e = order[pos];
                s = srcs[pos];
                x = r_ij[3*e]; y = r_ij[3*e+1]; z = r_ij[3*e+2];
            }
        }
        float r = sqrtf(x*x + y*y + z*z);
        float u = r * 4.0f;               // r * 8/R0, R0=2
        s16x8 ev;
        #pragma unroll
        for (int k = 0; k < 8; k++) {
            float t = fmaxf(1.0f - fabsf(u - (float)k), 0.0f);
            ev[k] = (short)f2bf((s >= 0) ? t : 0.0f);
        }
        *(s16x8*)&h_s[ml * 104 + 96] = ev;     // enc into pad cols
        float nn = 3.5f * r;
        float sc = (s >= 0) ? (3.5f * tanhf(nn) / fmaxf(nn, 1e-12f)) : 0.0f;
        rvb_s[0*128 + ml] = f2bf(x * sc);
        rvb_s[1*128 + ml] = f2bf(y * sc);
        rvb_s[2*128 + ml] = f2bf(z * sc);
        src_s[ml] = s;
    }
    __syncthreads();   // SYNC#1: src_s/enc visible

    // ---- wave 0: build segid / segnode / nseg (ballot-based prefix)
    if (w == 0) {
        int i = l;
        int sA = src_s[i];
        bool fA = (i == 0) || (sA != src_s[i - 1]);
        unsigned long long mA = __ballot(fA);
        unsigned long long maskA = (~0ull) >> (63 - i);
        int incA = (int)__popcll(mA & maskA);
        segid_s[i] = (unsigned char)(incA - 1);
        if (fA) segnode_s[incA - 1] = sA;
        int totA = (int)__popcll(mA);
        int jrow = 64 + i;
        int sB = src_s[jrow];
        bool fB = (sB != src_s[jrow - 1]);
        unsigned long long mB = __ballot(fB);
        int incB = (int)__popcll(mB & maskA);
        segid_s[jrow] = (unsigned char)(totA + incB - 1);
        if (fB) segnode_s[totA + incB - 1] = sB;
        if (i == 63) nseg_s = totA + (int)__popcll(mB);
    }

    float b0v[6], b1v[6], b2v[6];
    #pragma unroll
    for (int nt = 0; nt < 6; nt++) {
        b0v[nt] = b0[nt*16 + lr];
        b1v[nt] = b1[nt*16 + lr];
        b2v[nt] = b2[nt*16 + lr];
    }

    // ---- layer 0: h = enc @ w0.T + b0 (bias in C-init; enc in pad cols)
    {
        s16x8 A0[2];
        #pragma unroll
        for (int mf = 0; mf < 2; mf++) {
            s16x8 a = {0,0,0,0,0,0,0,0};
            if (l < 16) a = *(const s16x8*)&h_s[(mbase + mf*16 + lr) * 104 + 96];
            A0[mf] = a;
        }
        f32x4 acc[2][6];
        #pragma unroll
        for (int nt = 0; nt < 6; nt++) {
            s16x8 B = *(const s16x8*)&wp[nt * 512 + l * 8];
            f32x4 bi = {b0v[nt], b0v[nt], b0v[nt], b0v[nt]};
            acc[0][nt] = __builtin_amdgcn_mfma_f32_16x16x32_bf16(A0[0], B, bi, 0, 0, 0);
            acc[1][nt] = __builtin_amdgcn_mfma_f32_16x16x32_bf16(A0[1], B, bi, 0, 0, 0);
        }
        #pragma unroll
        for (int mf = 0; mf < 2; mf++)
        #pragma unroll
        for (int nt = 0; nt < 6; nt++)
        #pragma unroll
        for (int j = 0; j < 4; j++)
            h_s[(mbase + mf*16 + lg*4 + j) * 104 + nt*16 + lr] = f2bf(acc[mf][nt][j]);
    }

    // ---- layers 1,2: in-place leaky(h @ w.T + b); bias in C-init
    #pragma unroll
    for (int li = 0; li < 2; li++) {
        const int poff = 3072 + li * 9216;
        s16x8 A[2][3];
        #pragma unroll
        for (int mf = 0; mf < 2; mf++)
        #pragma unroll
        for (int kt = 0; kt < 3; kt++)
            A[mf][kt] = *(const s16x8*)&h_s[(mbase + mf*16 + lr) * 104 + kt*32 + lg*8];
        f32x4 a2[2][6];
        #pragma unroll
        for (int nt = 0; nt < 6; nt++) {
            float bb = (li == 0) ? b1v[nt] : b2v[nt];
            f32x4 bi = {bb, bb, bb, bb};
            a2[0][nt] = bi; a2[1][nt] = bi;
        }
        #pragma unroll
        for (int nt = 0; nt < 6; nt++)
        #pragma unroll
        for (int kt = 0; kt < 3; kt++) {
            s16x8 B = *(const s16x8*)&wp[poff + (kt*6 + nt) * 512 + l * 8];
            a2[0][nt] = __builtin_amdgcn_mfma_f32_16x16x32_bf16(A[0][kt], B, a2[0][nt], 0, 0, 0);
            a2[1][nt] = __builtin_amdgcn_mfma_f32_16x16x32_bf16(A[1][kt], B, a2[1][nt], 0, 0, 0);
        }
        #pragma unroll
        for (int mf = 0; mf < 2; mf++)
        #pragma unroll
        for (int nt = 0; nt < 6; nt++)
        #pragma unroll
        for (int j = 0; j < 4; j++) {
            float v = a2[mf][nt][j];
            v = fmaxf(v, 0.1f * v);
            h_s[(mbase + mf*16 + lg*4 + j) * 104 + nt*16 + lr] = f2bf(v);
        }
    }

    // ---- layer 3: rad = h @ w3.T -> packed regs only (frag stash after SYNC2)
    uint2 radp[2][6];
    {
        s16x8 A[2][3];
        #pragma unroll
        for (int mf = 0; mf < 2; mf++)
        #pragma unroll
        for (int kt = 0; kt < 3; kt++)
            A[mf][kt] = *(const s16x8*)&h_s[(mbase + mf*16 + lr) * 104 + kt*32 + lg*8];
        f32x4 rad[2][6] = {};
        #pragma unroll
        for (int nt = 0; nt < 6; nt++)
        #pragma unroll
        for (int kt = 0; kt < 3; kt++) {
            s16x8 B = *(const s16x8*)&wp[21504 + (kt*6 + nt) * 512 + l * 8];
            rad[0][nt] = __builtin_amdgcn_mfma_f32_16x16x32_bf16(A[0][kt], B, rad[0][nt], 0, 0, 0);
            rad[1][nt] = __builtin_amdgcn_mfma_f32_16x16x32_bf16(A[1][kt], B, rad[1][nt], 0, 0, 0);
        }
        #pragma unroll
        for (int mf = 0; mf < 2; mf++)
        #pragma unroll
        for (int nt = 0; nt < 6; nt++) {
            unsigned short q0 = f2bf(rad[mf][nt][0]);
            unsigned short q1 = f2bf(rad[mf][nt][1]);
            unsigned short q2 = f2bf(rad[mf][nt][2]);
            unsigned short q3 = f2bf(rad[mf][nt][3]);
            radp[mf][nt].x = (unsigned)q0 | ((unsigned)q1 << 16);
            radp[mf][nt].y = (unsigned)q2 | ((unsigned)q3 << 16);
        }
    }

    __syncthreads();   // SYNC#2: all row-major reads of h done -> overlay allowed

    // ---- rad -> B-fragment-order stash (overlays h_s[0 .. 12288 u16))
    #pragma unroll
    for (int mf = 0; mf < 2; mf++)
    #pragma unroll
    for (int nt = 0; nt < 6; nt++)
        *(uint2*)&h_s[(w*6 + nt) * 512 + ((2*mf + (lg>>1))*16 + lr) * 8 + (lg&1)*4] = radp[mf][nt];

    __syncthreads();   // SYNC#3: rad frags + segid visible

    // ---- segment reduction
    const int nseg = nseg_s;
    if (w == 0) {
        // A_a[seg][feat] = I @ rad
        for (int st = 0; st * 16 < nseg; ++st) {
            const int target = st * 16 + lr;
            f32x4 acc[6] = {};
            #pragma unroll
            for (int kt = 0; kt < 4; kt++) {
                uint2 sid8 = *(const uint2*)&segid_s[kt*32 + 8*lg];
                s16x8 af;
                #pragma unroll
                for (int j = 0; j < 8; j++) {
                    unsigned word = (j < 4) ? sid8.x : sid8.y;
                    int sid = (word >> (8 * (j & 3))) & 255;
                    af[j] = (short)((sid == target) ? 0x3F80 : 0);
                }
                #pragma unroll
                for (int nt = 0; nt < 6; nt++) {
                    s16x8 B = *(const s16x8*)&h_s[(kt*6 + nt) * 512 + l * 8];
                    acc[nt] = __builtin_amdgcn_mfma_f32_16x16x32_bf16(af, B, acc[nt], 0, 0, 0);
                }
            }
            #pragma unroll
            for (int nt = 0; nt < 6; nt++)
            #pragma unroll
            for (int j = 0; j < 4; j++) {
                int g = st*16 + 4*lg + j;
                if (g < nseg) {
                    int node = segnode_s[g];
                    if (node >= 0)
                        unsafeAtomicAdd(&A_a[node*96 + nt*16 + lr], acc[nt][j]);
                }
            }
        }
    } else {
        // S_c[seg][feat] = (I.rv_c) @ rad; stash as A-frags; Ov = S_c @ wv^T
        const int c = w - 1;
        const int scb = 12288 + (w - 1) * 1536;
        for (int st = 0; st * 16 < nseg; ++st) {
            const int target = st * 16 + lr;
            f32x4 acc6[6] = {};
            #pragma unroll
            for (int kt = 0; kt < 4; kt++) {
                uint2 sid8 = *(const uint2*)&segid_s[kt*32 + 8*lg];
                s16x8 rv8 = *(const s16x8*)&rvb_s[c*128 + kt*32 + 8*lg];
                s16x8 af;
                #pragma unroll
                for (int j = 0; j < 8; j++) {
                    unsigned word = (j < 4) ? sid8.x : sid8.y;
                    int sid = (word >> (8 * (j & 3))) & 255;
                    af[j] = (sid == target) ? rv8[j] : (short)0;
                }
                #pragma unroll
                for (int nt = 0; nt < 6; nt++) {
                    s16x8 B = *(const s16x8*)&h_s[(kt*6 + nt) * 512 + l * 8];
                    acc6[nt] = __builtin_amdgcn_mfma_f32_16x16x32_bf16(af, B, acc6[nt], 0, 0, 0);
                }
            }
            // stash S_c (C layout: seg=4lg+j, feat=16nt+lr) into A-frag order:
            // frag ktf=feat>>5; lane'=((feat&31)>>3)*16+seg; elem=feat&7
            #pragma unroll
            for (int nt = 0; nt < 6; nt++) {
                int ktf = nt >> 1;
                int lane2 = ((nt & 1) * 2 + (lr >> 3)) * 16 + 4*lg;
                int a0 = scb + ktf*512 + lane2*8 + (lr & 7);
                h_s[a0]      = f2bf(acc6[nt][0]);
                h_s[a0 + 8]  = f2bf(acc6[nt][1]);
                h_s[a0 + 16] = f2bf(acc6[nt][2]);
                h_s[a0 + 24] = f2bf(acc6[nt][3]);
            }
            // wv GEMM: D[seg][v] = S_c @ wv^T  (wave-private stash; in-wave RAW)
            s16x8 As[3];
            #pragma unroll
            for (int ktf = 0; ktf < 3; ktf++)
                As[ktf] = *(const s16x8*)&h_s[scb + ktf*512 + l*8];
            f32x4 acc2[4] = {};
            #pragma unroll
            for (int vt = 0; vt < 4; vt++)
            #pragma unroll
            for (int ktf = 0; ktf < 3; ktf++) {
                s16x8 B = *(const s16x8*)&wp[30720 + (ktf*4 + vt) * 512 + l * 8];
                acc2[vt] = __builtin_amdgcn_mfma_f32_16x16x32_bf16(As[ktf], B, acc2[vt], 0, 0, 0);
            }
            #pragma unroll
            for (int vt = 0; vt < 4; vt++)
            #pragma unroll
            for (int j = 0; j < 4; j++) {
                int g = st*16 + 4*lg + j;
                if (g < nseg) {
                    int node = segnode_s[g];
                    if (node >= 0)
                        unsafeAtomicAdd(&Ov[node*192 + (vt*16 + lr)*3 + c], acc2[vt][j]);
                }
            }
        }
    }
}

extern "C" void kernel_launch(void* const* d_in, const int* in_sizes, int n_in,
                              void* d_out, int out_size, void* d_ws, size_t ws_size,
                              hipStream_t stream)
{
    const float* r_ij = (const float*)d_in[0];
    const float* w0   = (const float*)d_in[1];
    const float* b0   = (const float*)d_in[2];
    const float* w1   = (const float*)d_in[3];
    const float* b1   = (const float*)d_in[4];
    const float* w2   = (const float*)d_in[5];
    const float* b2   = (const float*)d_in[6];
    const float* w3   = (const float*)d_in[7];
    const float* wv   = (const float*)d_in[8];
    const int*   src  = (const int*)d_in[9];
    const int E = in_sizes[0] / 3;
    const int N = out_size / 288;
    float* A_a = (float*)d_out;
    float* Ov  = A_a + (size_t)N * 96;

    char* wsb = (char*)d_ws;
    unsigned short* wp = (unsigned short*)wsb;                  // 73728 B
    size_t off = 73728;
    int* counts = (int*)(wsb + off);  off += (((size_t)N*4 + 127) & ~127ull);
    int* cursor = (int*)(wsb + off);  off += (((size_t)N*4 + 127) & ~127ull);
    int* bsum   = (int*)(wsb + off);  off += 256;
    size_t need_rsrt = off + (size_t)E * 16;
    int use_rsrt = (need_rsrt <= ws_size) ? 1 : 0;
    float4* rsrt = (float4*)(wsb + off);
    int* order   = (int*)(wsb + off);
    int* srcs    = (int*)(wsb + off + (((size_t)E*4 + 127) & ~127ull));

    const int nb = (N + 2047) / 2048;

    hipMemsetAsync(d_out, 0, (size_t)out_size * sizeof(float), stream);
    hipMemsetAsync(counts, 0, (size_t)N * 4, stream);

    pack_weights_k<<<(PACK_TOT + 255) / 256, 256, 0, stream>>>(w0, w1, w2, w3, wv, wp);
    hist_k<<<(E + 255) / 256, 256, 0, stream>>>(src, counts, E);
    scan1_k<<<nb, 256, 0, stream>>>(counts, cursor, bsum, N);
    scan2_k<<<1, 64, 0, stream>>>(bsum, nb);
    scatter_k<<<(E + 255) / 256, 256, 0, stream>>>(src, r_ij, bsum, cursor,
                                                   order, srcs, rsrt, use_rsrt, E);
    edge_kernel<<<(E + 127) / 128, 256, 0, stream>>>(r_ij, order, srcs, rsrt, use_rsrt,
                                                     wp, b0, b1, b2, A_a, Ov, E);
}

// Round 10
// 271.784 us; speedup vs baseline: 1.0096x; 1.0096x over previous
//
#include <hip/hip_runtime.h>
#include <math.h>

typedef float f32x4 __attribute__((ext_vector_type(4)));
typedef short s16x8 __attribute__((ext_vector_type(8)));

__device__ __forceinline__ unsigned short f2bf(float f) {
    unsigned u = __builtin_bit_cast(unsigned, f);
    u += 0x7fffu + ((u >> 16) & 1u);
    return (unsigned short)(u >> 16);
}

// Bijective XCD-chunking swizzle (m204 form): hw block b lands on XCD b%8;
// give XCD x the contiguous work chunk [base_x, base_x+count_x). Consecutive
// WORK ids (= consecutive sorted-node ranges) then share one XCD's L2, so
// atomic output lines stop ping-ponging between non-coherent per-XCD L2s.
__device__ __forceinline__ int xcd_swizzle(int b, int nwg) {
    int q = nwg >> 3, r = nwg & 7;
    int xcd = b & 7, slot = b >> 3;
    int base = (xcd < r) ? xcd * (q + 1) : r * (q + 1) + (xcd - r) * q;
    return base + slot;
}

// ---------------- weight packing ----------------
// B-frag order: frag (kt,nt): lane l elem j holds W[n=16nt+(l&15)][k=32kt+8*(l>>4)+j]
#define PACK_TOT 36864

__global__ __launch_bounds__(256) void pack_weights_k(
    const float* __restrict__ w0, const float* __restrict__ w1,
    const float* __restrict__ w2, const float* __restrict__ w3,
    const float* __restrict__ wv, unsigned short* __restrict__ dst)
{
    int idx = blockIdx.x * 256 + threadIdx.x;
    if (idx >= PACK_TOT) return;
    const float* W; int inF, ntiles, off;
    if (idx < 3072)       { W = w0; inF = 8;  ntiles = 6; off = 0; }
    else if (idx < 12288) { W = w1; inF = 96; ntiles = 6; off = 3072; }
    else if (idx < 21504) { W = w2; inF = 96; ntiles = 6; off = 12288; }
    else if (idx < 30720) { W = w3; inF = 96; ntiles = 6; off = 21504; }
    else                  { W = wv; inF = 96; ntiles = 4; off = 30720; }
    int r  = idx - off;
    int fi = r >> 9;
    int wi = r & 511;
    int l = wi >> 3, j = wi & 7;
    int kt = fi / ntiles, nt = fi - kt * ntiles;
    int n = nt * 16 + (l & 15);
    int k = kt * 32 + ((l >> 4) << 3) + j;
    float v = (k < inF) ? W[n * inF + k] : 0.0f;
    dst[idx] = f2bf(v);
}

// ---------------- CSR build ----------------
__global__ __launch_bounds__(256) void hist_k(const int* __restrict__ src,
                                              int* __restrict__ counts, int E)
{
    int e = blockIdx.x * 256 + threadIdx.x;
    if (e < E) atomicAdd(&counts[src[e]], 1);
}

__global__ __launch_bounds__(256) void scan1_k(const int* __restrict__ counts,
                                               int* __restrict__ cursor,
                                               int* __restrict__ bsum, int N)
{
    __shared__ int wsum_s[4];
    int b = blockIdx.x, t = threadIdx.x, lane = t & 63, wid = t >> 6;
    int i0 = b * 2048 + t * 8;
    int v[8]; int s = 0;
    #pragma unroll
    for (int j = 0; j < 8; j++) { int i = i0 + j; v[j] = (i < N) ? counts[i] : 0; s += v[j]; }
    int inc = s;
    #pragma unroll
    for (int d = 1; d < 64; d <<= 1) { int o = __shfl_up(inc, d, 64); if (lane >= d) inc += o; }
    if (lane == 63) wsum_s[wid] = inc;
    __syncthreads();
    int wb = 0;
    for (int k = 0; k < wid; k++) wb += wsum_s[k];
    int run = wb + inc - s;
    #pragma unroll
    for (int j = 0; j < 8; j++) { int i = i0 + j; if (i < N) cursor[i] = run; run += v[j]; }
    if (t == 255) bsum[b] = wb + inc;
}

__global__ __launch_bounds__(64) void scan2_k(int* __restrict__ bsum, int nb)
{
    int lane = threadIdx.x;
    int v = (lane < nb) ? bsum[lane] : 0;
    int inc = v;
    #pragma unroll
    for (int d = 1; d < 64; d <<= 1) { int o = __shfl_up(inc, d, 64); if (lane >= d) inc += o; }
    if (lane < nb) bsum[lane] = inc - v;
}

__global__ __launch_bounds__(256) void scatter_k(const int* __restrict__ src,
                                                 const float* __restrict__ r_ij,
                                                 const int* __restrict__ bsum,
                                                 int* __restrict__ cursor,
                                                 int* __restrict__ order,
                                                 int* __restrict__ srcs,
                                                 float4* __restrict__ rsrt,
                                                 int use_rsrt, int E)
{
    int e = blockIdx.x * 256 + threadIdx.x;
    if (e < E) {
        int s = src[e];
        int p = bsum[s >> 11] + atomicAdd(&cursor[s], 1);
        if (use_rsrt) {
            rsrt[p] = make_float4(r_ij[3*e], r_ij[3*e+1], r_ij[3*e+2], __int_as_float(s));
        } else {
            order[p] = e;
            srcs[p] = s;
        }
    }
}

// ---------------- fused edge kernel ----------------
// r9-passing structure (bias in C-init, leaky=fmax(x,0.1x), wv push-down,
// 4 blocks/CU) + XCD-chunked block swizzle for atomic L2 locality.
__global__ __launch_bounds__(256, 4) void edge_kernel(
    const float* __restrict__ r_ij,
    const int* __restrict__ order, const int* __restrict__ srcs,
    const float4* __restrict__ rsrt, int use_rsrt,
    const unsigned short* __restrict__ wp,
    const float* __restrict__ b0, const float* __restrict__ b1, const float* __restrict__ b2,
    float* __restrict__ A_a, float* __restrict__ Ov, int E)
{
    // [0..13312): row-major MLP buffer (stride 104, cols 96..103 = enc)
    // after SYNC2 overlay: [0..12288) = 24 rad B-frags (512 u16 each)
    // [12288..16896): per-wave S_c A-frag scratch for waves 1..3
    __shared__ unsigned short h_s[16896];
    __shared__ unsigned short rvb_s[3 * 128];      // bf16 rv, [c][row]
    __shared__ unsigned char  segid_s[128];
    __shared__ int  segnode_s[128];
    __shared__ int  src_s[128];
    __shared__ int  nseg_s;

    const int tid = threadIdx.x;
    const int w  = tid >> 6;
    const int l  = tid & 63;
    const int e0 = xcd_swizzle(blockIdx.x, gridDim.x) * 128;
    const int lr = l & 15;
    const int lg = l >> 4;
    const int mbase = w * 32;

    // ---- stage per-edge scalars (coalesced float4 fast path)
    if (l < 32) {
        const int ml = mbase + l;
        const int pos = e0 + ml;
        float x = 0.f, y = 0.f, z = 0.f; int s = -1;
        if (pos < E) {
            if (use_rsrt) {
                float4 v4 = rsrt[pos];
                x = v4.x; y = v4.y; z = v4.z; s = __float_as_int(v4.w);
            } else {
                int e = order[pos];
                s = srcs[pos];
                x = r_ij[3*e]; y = r_ij[3*e+1]; z = r_ij[3*e+2];
            }
        }
        float r = sqrtf(x*x + y*y + z*z);
        float u = r * 4.0f;               // r * 8/R0, R0=2
        s16x8 ev;
        #pragma unroll
        for (int k = 0; k < 8; k++) {
            float t = fmaxf(1.0f - fabsf(u - (float)k), 0.0f);
            ev[k] = (short)f2bf((s >= 0) ? t : 0.0f);
        }
        *(s16x8*)&h_s[ml * 104 + 96] = ev;     // enc into pad cols
        float nn = 3.5f * r;
        float sc = (s >= 0) ? (3.5f * tanhf(nn) / fmaxf(nn, 1e-12f)) : 0.0f;
        rvb_s[0*128 + ml] = f2bf(x * sc);
        rvb_s[1*128 + ml] = f2bf(y * sc);
        rvb_s[2*128 + ml] = f2bf(z * sc);
        src_s[ml] = s;
    }
    __syncthreads();   // SYNC#1: src_s/enc visible

    // ---- wave 0: build segid / segnode / nseg (ballot-based prefix)
    if (w == 0) {
        int i = l;
        int sA = src_s[i];
        bool fA = (i == 0) || (sA != src_s[i - 1]);
        unsigned long long mA = __ballot(fA);
        unsigned long long maskA = (~0ull) >> (63 - i);
        int incA = (int)__popcll(mA & maskA);
        segid_s[i] = (unsigned char)(incA - 1);
        if (fA) segnode_s[incA - 1] = sA;
        int totA = (int)__popcll(mA);
        int jrow = 64 + i;
        int sB = src_s[jrow];
        bool fB = (sB != src_s[jrow - 1]);
        unsigned long long mB = __ballot(fB);
        int incB = (int)__popcll(mB & maskA);
        segid_s[jrow] = (unsigned char)(totA + incB - 1);
        if (fB) segnode_s[totA + incB - 1] = sB;
        if (i == 63) nseg_s = totA + (int)__popcll(mB);
    }

    float b0v[6], b1v[6], b2v[6];
    #pragma unroll
    for (int nt = 0; nt < 6; nt++) {
        b0v[nt] = b0[nt*16 + lr];
        b1v[nt] = b1[nt*16 + lr];
        b2v[nt] = b2[nt*16 + lr];
    }

    // ---- layer 0: h = enc @ w0.T + b0 (bias in C-init; enc in pad cols)
    {
        s16x8 A0[2];
        #pragma unroll
        for (int mf = 0; mf < 2; mf++) {
            s16x8 a = {0,0,0,0,0,0,0,0};
            if (l < 16) a = *(const s16x8*)&h_s[(mbase + mf*16 + lr) * 104 + 96];
            A0[mf] = a;
        }
        f32x4 acc[2][6];
        #pragma unroll
        for (int nt = 0; nt < 6; nt++) {
            s16x8 B = *(const s16x8*)&wp[nt * 512 + l * 8];
            f32x4 bi = {b0v[nt], b0v[nt], b0v[nt], b0v[nt]};
            acc[0][nt] = __builtin_amdgcn_mfma_f32_16x16x32_bf16(A0[0], B, bi, 0, 0, 0);
            acc[1][nt] = __builtin_amdgcn_mfma_f32_16x16x32_bf16(A0[1], B, bi, 0, 0, 0);
        }
        #pragma unroll
        for (int mf = 0; mf < 2; mf++)
        #pragma unroll
        for (int nt = 0; nt < 6; nt++)
        #pragma unroll
        for (int j = 0; j < 4; j++)
            h_s[(mbase + mf*16 + lg*4 + j) * 104 + nt*16 + lr] = f2bf(acc[mf][nt][j]);
    }

    // ---- layers 1,2: in-place leaky(h @ w.T + b); bias in C-init
    #pragma unroll
    for (int li = 0; li < 2; li++) {
        const int poff = 3072 + li * 9216;
        s16x8 A[2][3];
        #pragma unroll
        for (int mf = 0; mf < 2; mf++)
        #pragma unroll
        for (int kt = 0; kt < 3; kt++)
            A[mf][kt] = *(const s16x8*)&h_s[(mbase + mf*16 + lr) * 104 + kt*32 + lg*8];
        f32x4 a2[2][6];
        #pragma unroll
        for (int nt = 0; nt < 6; nt++) {
            float bb = (li == 0) ? b1v[nt] : b2v[nt];
            f32x4 bi = {bb, bb, bb, bb};
            a2[0][nt] = bi; a2[1][nt] = bi;
        }
        #pragma unroll
        for (int nt = 0; nt < 6; nt++)
        #pragma unroll
        for (int kt = 0; kt < 3; kt++) {
            s16x8 B = *(const s16x8*)&wp[poff + (kt*6 + nt) * 512 + l * 8];
            a2[0][nt] = __builtin_amdgcn_mfma_f32_16x16x32_bf16(A[0][kt], B, a2[0][nt], 0, 0, 0);
            a2[1][nt] = __builtin_amdgcn_mfma_f32_16x16x32_bf16(A[1][kt], B, a2[1][nt], 0, 0, 0);
        }
        #pragma unroll
        for (int mf = 0; mf < 2; mf++)
        #pragma unroll
        for (int nt = 0; nt < 6; nt++)
        #pragma unroll
        for (int j = 0; j < 4; j++) {
            float v = a2[mf][nt][j];
            v = fmaxf(v, 0.1f * v);
            h_s[(mbase + mf*16 + lg*4 + j) * 104 + nt*16 + lr] = f2bf(v);
        }
    }

    // ---- layer 3: rad = h @ w3.T -> packed regs only (frag stash after SYNC2)
    uint2 radp[2][6];
    {
        s16x8 A[2][3];
        #pragma unroll
        for (int mf = 0; mf < 2; mf++)
        #pragma unroll
        for (int kt = 0; kt < 3; kt++)
            A[mf][kt] = *(const s16x8*)&h_s[(mbase + mf*16 + lr) * 104 + kt*32 + lg*8];
        f32x4 rad[2][6] = {};
        #pragma unroll
        for (int nt = 0; nt < 6; nt++)
        #pragma unroll
        for (int kt = 0; kt < 3; kt++) {
            s16x8 B = *(const s16x8*)&wp[21504 + (kt*6 + nt) * 512 + l * 8];
            rad[0][nt] = __builtin_amdgcn_mfma_f32_16x16x32_bf16(A[0][kt], B, rad[0][nt], 0, 0, 0);
            rad[1][nt] = __builtin_amdgcn_mfma_f32_16x16x32_bf16(A[1][kt], B, rad[1][nt], 0, 0, 0);
        }
        #pragma unroll
        for (int mf = 0; mf < 2; mf++)
        #pragma unroll
        for (int nt = 0; nt < 6; nt++) {
            unsigned short q0 = f2bf(rad[mf][nt][0]);
            unsigned short q1 = f2bf(rad[mf][nt][1]);
            unsigned short q2 = f2bf(rad[mf][nt][2]);
            unsigned short q3 = f2bf(rad[mf][nt][3]);
            radp[mf][nt].x = (unsigned)q0 | ((unsigned)q1 << 16);
            radp[mf][nt].y = (unsigned)q2 | ((unsigned)q3 << 16);
        }
    }

    __syncthreads();   // SYNC#2: all row-major reads of h done -> overlay allowed

    // ---- rad -> B-fragment-order stash (overlays h_s[0 .. 12288 u16))
    #pragma unroll
    for (int mf = 0; mf < 2; mf++)
    #pragma unroll
    for (int nt = 0; nt < 6; nt++)
        *(uint2*)&h_s[(w*6 + nt) * 512 + ((2*mf + (lg>>1))*16 + lr) * 8 + (lg&1)*4] = radp[mf][nt];

    __syncthreads();   // SYNC#3: rad frags + segid visible

    // ---- segment reduction
    const int nseg = nseg_s;
    if (w == 0) {
        // A_a[seg][feat] = I @ rad
        for (int st = 0; st * 16 < nseg; ++st) {
            const int target = st * 16 + lr;
            f32x4 acc[6] = {};
            #pragma unroll
            for (int kt = 0; kt < 4; kt++) {
                uint2 sid8 = *(const uint2*)&segid_s[kt*32 + 8*lg];
                s16x8 af;
                #pragma unroll
                for (int j = 0; j < 8; j++) {
                    unsigned word = (j < 4) ? sid8.x : sid8.y;
                    int sid = (word >> (8 * (j & 3))) & 255;
                    af[j] = (short)((sid == target) ? 0x3F80 : 0);
                }
                #pragma unroll
                for (int nt = 0; nt < 6; nt++) {
                    s16x8 B = *(const s16x8*)&h_s[(kt*6 + nt) * 512 + l * 8];
                    acc[nt] = __builtin_amdgcn_mfma_f32_16x16x32_bf16(af, B, acc[nt], 0, 0, 0);
                }
            }
            #pragma unroll
            for (int nt = 0; nt < 6; nt++)
            #pragma unroll
            for (int j = 0; j < 4; j++) {
                int g = st*16 + 4*lg + j;
                if (g < nseg) {
                    int node = segnode_s[g];
                    if (node >= 0)
                        unsafeAtomicAdd(&A_a[node*96 + nt*16 + lr], acc[nt][j]);
                }
            }
        }
    } else {
        // S_c[seg][feat] = (I.rv_c) @ rad; stash as A-frags; Ov = S_c @ wv^T
        const int c = w - 1;
        const int scb = 12288 + (w - 1) * 1536;
        for (int st = 0; st * 16 < nseg; ++st) {
            const int target = st * 16 + lr;
            f32x4 acc6[6] = {};
            #pragma unroll
            for (int kt = 0; kt < 4; kt++) {
                uint2 sid8 = *(const uint2*)&segid_s[kt*32 + 8*lg];
                s16x8 rv8 = *(const s16x8*)&rvb_s[c*128 + kt*32 + 8*lg];
                s16x8 af;
                #pragma unroll
                for (int j = 0; j < 8; j++) {
                    unsigned word = (j < 4) ? sid8.x : sid8.y;
                    int sid = (word >> (8 * (j & 3))) & 255;
                    af[j] = (sid == target) ? rv8[j] : (short)0;
                }
                #pragma unroll
                for (int nt = 0; nt < 6; nt++) {
                    s16x8 B = *(const s16x8*)&h_s[(kt*6 + nt) * 512 + l * 8];
                    acc6[nt] = __builtin_amdgcn_mfma_f32_16x16x32_bf16(af, B, acc6[nt], 0, 0, 0);
                }
            }
            // stash S_c (C layout: seg=4lg+j, feat=16nt+lr) into A-frag order:
            // frag ktf=feat>>5; lane'=((feat&31)>>3)*16+seg; elem=feat&7
            #pragma unroll
            for (int nt = 0; nt < 6; nt++) {
                int ktf = nt >> 1;
                int lane2 = ((nt & 1) * 2 + (lr >> 3)) * 16 + 4*lg;
                int a0 = scb + ktf*512 + lane2*8 + (lr & 7);
                h_s[a0]      = f2bf(acc6[nt][0]);
                h_s[a0 + 8]  = f2bf(acc6[nt][1]);
                h_s[a0 + 16] = f2bf(acc6[nt][2]);
                h_s[a0 + 24] = f2bf(acc6[nt][3]);
            }
            // wv GEMM: D[seg][v] = S_c @ wv^T  (wave-private stash; in-wave RAW)
            s16x8 As[3];
            #pragma unroll
            for (int ktf = 0; ktf < 3; ktf++)
                As[ktf] = *(const s16x8*)&h_s[scb + ktf*512 + l*8];
            f32x4 acc2[4] = {};
            #pragma unroll
            for (int vt = 0; vt < 4; vt++)
            #pragma unroll
            for (int ktf = 0; ktf < 3; ktf++) {
                s16x8 B = *(const s16x8*)&wp[30720 + (ktf*4 + vt) * 512 + l * 8];
                acc2[vt] = __builtin_amdgcn_mfma_f32_16x16x32_bf16(As[ktf], B, acc2[vt], 0, 0, 0);
            }
            #pragma unroll
            for (int vt = 0; vt < 4; vt++)
            #pragma unroll
            for (int j = 0; j < 4; j++) {
                int g = st*16 + 4*lg + j;
                if (g < nseg) {
                    int node = segnode_s[g];
                    if (node >= 0)
                        unsafeAtomicAdd(&Ov[node*192 + (vt*16 + lr)*3 + c], acc2[vt][j]);
                }
            }
        }
    }
}

extern "C" void kernel_launch(void* const* d_in, const int* in_sizes, int n_in,
                              void* d_out, int out_size, void* d_ws, size_t ws_size,
                              hipStream_t stream)
{
    const float* r_ij = (const float*)d_in[0];
    const float* w0   = (const float*)d_in[1];
    const float* b0   = (const float*)d_in[2];
    const float* w1   = (const float*)d_in[3];
    const float* b1   = (const float*)d_in[4];
    const float* w2   = (const float*)d_in[5];
    const float* b2   = (const float*)d_in[6];
    const float* w3   = (const float*)d_in[7];
    const float* wv   = (const float*)d_in[8];
    const int*   src  = (const int*)d_in[9];
    const int E = in_sizes[0] / 3;
    const int N = out_size / 288;
    float* A_a = (float*)d_out;
    float* Ov  = A_a + (size_t)N * 96;

    char* wsb = (char*)d_ws;
    unsigned short* wp = (unsigned short*)wsb;                  // 73728 B
    size_t off = 73728;
    int* counts = (int*)(wsb + off);  off += (((size_t)N*4 + 127) & ~127ull);
    int* cursor = (int*)(wsb + off);  off += (((size_t)N*4 + 127) & ~127ull);
    int* bsum   = (int*)(wsb + off);  off += 256;
    size_t need_rsrt = off + (size_t)E * 16;
    int use_rsrt = (need_rsrt <= ws_size) ? 1 : 0;
    float4* rsrt = (float4*)(wsb + off);
    int* order   = (int*)(wsb + off);
    int* srcs    = (int*)(wsb + off + (((size_t)E*4 + 127) & ~127ull));

    const int nb = (N + 2047) / 2048;

    hipMemsetAsync(d_out, 0, (size_t)out_size * sizeof(float), stream);
    hipMemsetAsync(counts, 0, (size_t)N * 4, stream);

    pack_weights_k<<<(PACK_TOT + 255) / 256, 256, 0, stream>>>(w0, w1, w2, w3, wv, wp);
    hist_k<<<(E + 255) / 256, 256, 0, stream>>>(src, counts, E);
    scan1_k<<<nb, 256, 0, stream>>>(counts, cursor, bsum, N);
    scan2_k<<<1, 64, 0, stream>>>(bsum, nb);
    scatter_k<<<(E + 255) / 256, 256, 0, stream>>>(src, r_ij, bsum, cursor,
                                                   order, srcs, rsrt, use_rsrt, E);
    edge_kernel<<<(E + 127) / 128, 256, 0, stream>>>(r_ij, order, srcs, rsrt, use_rsrt,
                                                     wp, b0, b1, b2, A_a, Ov, E);
}

// Round 11
// 255.434 us; speedup vs baseline: 1.0742x; 1.0640x over previous
//
#include <hip/hip_runtime.h>
#include <math.h>

typedef float f32x4 __attribute__((ext_vector_type(4)));
typedef short s16x8 __attribute__((ext_vector_type(8)));

__device__ __forceinline__ unsigned short f2bf(float f) {
    unsigned u = __builtin_bit_cast(unsigned, f);
    u += 0x7fffu + ((u >> 16) & 1u);
    return (unsigned short)(u >> 16);
}

// Bijective XCD-chunking swizzle (m204 form). Null at 4 blocks/CU (r10) but
// harmless; kept so this round's only edge-kernel change is the occupancy bound.
__device__ __forceinline__ int xcd_swizzle(int b, int nwg) {
    int q = nwg >> 3, r = nwg & 7;
    int xcd = b & 7, slot = b >> 3;
    int base = (xcd < r) ? xcd * (q + 1) : r * (q + 1) + (xcd - r) * q;
    return base + slot;
}

// ---------------- weight packing ----------------
// B-frag order: frag (kt,nt): lane l elem j holds W[n=16nt+(l&15)][k=32kt+8*(l>>4)+j]
#define PACK_TOT 36864

__global__ __launch_bounds__(256) void pack_weights_k(
    const float* __restrict__ w0, const float* __restrict__ w1,
    const float* __restrict__ w2, const float* __restrict__ w3,
    const float* __restrict__ wv, unsigned short* __restrict__ dst)
{
    int idx = blockIdx.x * 256 + threadIdx.x;
    if (idx >= PACK_TOT) return;
    const float* W; int inF, ntiles, off;
    if (idx < 3072)       { W = w0; inF = 8;  ntiles = 6; off = 0; }
    else if (idx < 12288) { W = w1; inF = 96; ntiles = 6; off = 3072; }
    else if (idx < 21504) { W = w2; inF = 96; ntiles = 6; off = 12288; }
    else if (idx < 30720) { W = w3; inF = 96; ntiles = 6; off = 21504; }
    else                  { W = wv; inF = 96; ntiles = 4; off = 30720; }
    int r  = idx - off;
    int fi = r >> 9;
    int wi = r & 511;
    int l = wi >> 3, j = wi & 7;
    int kt = fi / ntiles, nt = fi - kt * ntiles;
    int n = nt * 16 + (l & 15);
    int k = kt * 32 + ((l >> 4) << 3) + j;
    float v = (k < inF) ? W[n * inF + k] : 0.0f;
    dst[idx] = f2bf(v);
}

// ---------------- CSR build ----------------
__global__ __launch_bounds__(256) void hist_k(const int* __restrict__ src,
                                              int* __restrict__ counts, int E)
{
    int e = blockIdx.x * 256 + threadIdx.x;
    if (e < E) atomicAdd(&counts[src[e]], 1);
}

// multi-block scan: each block scans a 2048 chunk (within-chunk exclusive prefix);
// bsum[b] = chunk TOTAL (prefix of totals is computed inside scatter_k now).
__global__ __launch_bounds__(256) void scan1_k(const int* __restrict__ counts,
                                               int* __restrict__ cursor,
                                               int* __restrict__ bsum, int N)
{
    __shared__ int wsum_s[4];
    int b = blockIdx.x, t = threadIdx.x, lane = t & 63, wid = t >> 6;
    int i0 = b * 2048 + t * 8;
    int v[8]; int s = 0;
    #pragma unroll
    for (int j = 0; j < 8; j++) { int i = i0 + j; v[j] = (i < N) ? counts[i] : 0; s += v[j]; }
    int inc = s;
    #pragma unroll
    for (int d = 1; d < 64; d <<= 1) { int o = __shfl_up(inc, d, 64); if (lane >= d) inc += o; }
    if (lane == 63) wsum_s[wid] = inc;
    __syncthreads();
    int wb = 0;
    for (int k = 0; k < wid; k++) wb += wsum_s[k];
    int run = wb + inc - s;
    #pragma unroll
    for (int j = 0; j < 8; j++) { int i = i0 + j; if (i < N) cursor[i] = run; run += v[j]; }
    if (t == 255) bsum[b] = wb + inc;
}

// scatter with inline chunk-total prefix (replaces the scan2_k launch):
// wave 0 prefixes up to 256 chunk totals into pre_s, then all threads scatter.
__global__ __launch_bounds__(256) void scatter_k(const int* __restrict__ src,
                                                 const float* __restrict__ r_ij,
                                                 const int* __restrict__ bsum,
                                                 int* __restrict__ cursor,
                                                 int* __restrict__ order,
                                                 int* __restrict__ srcs,
                                                 float4* __restrict__ rsrt,
                                                 int use_rsrt, int nb, int E)
{
    __shared__ int pre_s[256];
    int t = threadIdx.x;
    if (t < 64) {
        int carry = 0;
        for (int base = 0; base < nb; base += 64) {
            int i = base + t;
            int v = (i < nb) ? bsum[i] : 0;
            int inc = v;
            #pragma unroll
            for (int d = 1; d < 64; d <<= 1) {
                int o = __shfl_up(inc, d, 64);
                if (t >= d) inc += o;
            }
            if (i < nb) pre_s[i] = carry + inc - v;   // exclusive prefix
            carry += __shfl(inc, 63);
        }
    }
    __syncthreads();
    int e = blockIdx.x * 256 + t;
    if (e < E) {
        int s = src[e];
        int p = pre_s[s >> 11] + atomicAdd(&cursor[s], 1);
        if (use_rsrt) {
            rsrt[p] = make_float4(r_ij[3*e], r_ij[3*e+1], r_ij[3*e+2], __int_as_float(s));
        } else {
            order[p] = e;
            srcs[p] = s;
        }
    }
}

// ---------------- fused edge kernel ----------------
// r10 kernel verbatim except __launch_bounds__(256,3): at 4 blocks/CU the
// concurrent atomic working set (~2.8MB/XCD) thrashes the 4MB L2 (r9/r10:
// FETCH+WRITE doubled vs r7 with identical atomics); 3 blocks/CU sits under
// the capacity knee.
__global__ __launch_bounds__(256, 3) void edge_kernel(
    const float* __restrict__ r_ij,
    const int* __restrict__ order, const int* __restrict__ srcs,
    const float4* __restrict__ rsrt, int use_rsrt,
    const unsigned short* __restrict__ wp,
    const float* __restrict__ b0, const float* __restrict__ b1, const float* __restrict__ b2,
    float* __restrict__ A_a, float* __restrict__ Ov, int E)
{
    // [0..13312): row-major MLP buffer (stride 104, cols 96..103 = enc)
    // after SYNC2 overlay: [0..12288) = 24 rad B-frags (512 u16 each)
    // [12288..16896): per-wave S_c A-frag scratch for waves 1..3
    __shared__ unsigned short h_s[16896];
    __shared__ unsigned short rvb_s[3 * 128];      // bf16 rv, [c][row]
    __shared__ unsigned char  segid_s[128];
    __shared__ int  segnode_s[128];
    __shared__ int  src_s[128];
    __shared__ int  nseg_s;

    const int tid = threadIdx.x;
    const int w  = tid >> 6;
    const int l  = tid & 63;
    const int e0 = xcd_swizzle(blockIdx.x, gridDim.x) * 128;
    const int lr = l & 15;
    const int lg = l >> 4;
    const int mbase = w * 32;

    // ---- stage per-edge scalars (coalesced float4 fast path)
    if (l < 32) {
        const int ml = mbase + l;
        const int pos = e0 + ml;
        float x = 0.f, y = 0.f, z = 0.f; int s = -1;
        if (pos < E) {
            if (use_rsrt) {
                float4 v4 = rsrt[pos];
                x = v4.x; y = v4.y; z = v4.z; s = __float_as_int(v4.w);
            } else {
                int e = order[pos];
                s = srcs[pos];
                x = r_ij[3*e]; y = r_ij[3*e+1]; z = r_ij[3*e+2];
            }
        }
        float r = sqrtf(x*x + y*y + z*z);
        float u = r * 4.0f;               // r * 8/R0, R0=2
        s16x8 ev;
        #pragma unroll
        for (int k = 0; k < 8; k++) {
            float t = fmaxf(1.0f - fabsf(u - (float)k), 0.0f);
            ev[k] = (short)f2bf((s >= 0) ? t : 0.0f);
        }
        *(s16x8*)&h_s[ml * 104 + 96] = ev;     // enc into pad cols
        float nn = 3.5f * r;
        float sc = (s >= 0) ? (3.5f * tanhf(nn) / fmaxf(nn, 1e-12f)) : 0.0f;
        rvb_s[0*128 + ml] = f2bf(x * sc);
        rvb_s[1*128 + ml] = f2bf(y * sc);
        rvb_s[2*128 + ml] = f2bf(z * sc);
        src_s[ml] = s;
    }
    __syncthreads();   // SYNC#1: src_s/enc visible

    // ---- wave 0: build segid / segnode / nseg (ballot-based prefix)
    if (w == 0) {
        int i = l;
        int sA = src_s[i];
        bool fA = (i == 0) || (sA != src_s[i - 1]);
        unsigned long long mA = __ballot(fA);
        unsigned long long maskA = (~0ull) >> (63 - i);
        int incA = (int)__popcll(mA & maskA);
        segid_s[i] = (unsigned char)(incA - 1);
        if (fA) segnode_s[incA - 1] = sA;
        int totA = (int)__popcll(mA);
        int jrow = 64 + i;
        int sB = src_s[jrow];
        bool fB = (sB != src_s[jrow - 1]);
        unsigned long long mB = __ballot(fB);
        int incB = (int)__popcll(mB & maskA);
        segid_s[jrow] = (unsigned char)(totA + incB - 1);
        if (fB) segnode_s[totA + incB - 1] = sB;
        if (i == 63) nseg_s = totA + (int)__popcll(mB);
    }

    float b0v[6], b1v[6], b2v[6];
    #pragma unroll
    for (int nt = 0; nt < 6; nt++) {
        b0v[nt] = b0[nt*16 + lr];
        b1v[nt] = b1[nt*16 + lr];
        b2v[nt] = b2[nt*16 + lr];
    }

    // ---- layer 0: h = enc @ w0.T + b0 (bias in C-init; enc in pad cols)
    {
        s16x8 A0[2];
        #pragma unroll
        for (int mf = 0; mf < 2; mf++) {
            s16x8 a = {0,0,0,0,0,0,0,0};
            if (l < 16) a = *(const s16x8*)&h_s[(mbase + mf*16 + lr) * 104 + 96];
            A0[mf] = a;
        }
        f32x4 acc[2][6];
        #pragma unroll
        for (int nt = 0; nt < 6; nt++) {
            s16x8 B = *(const s16x8*)&wp[nt * 512 + l * 8];
            f32x4 bi = {b0v[nt], b0v[nt], b0v[nt], b0v[nt]};
            acc[0][nt] = __builtin_amdgcn_mfma_f32_16x16x32_bf16(A0[0], B, bi, 0, 0, 0);
            acc[1][nt] = __builtin_amdgcn_mfma_f32_16x16x32_bf16(A0[1], B, bi, 0, 0, 0);
        }
        #pragma unroll
        for (int mf = 0; mf < 2; mf++)
        #pragma unroll
        for (int nt = 0; nt < 6; nt++)
        #pragma unroll
        for (int j = 0; j < 4; j++)
            h_s[(mbase + mf*16 + lg*4 + j) * 104 + nt*16 + lr] = f2bf(acc[mf][nt][j]);
    }

    // ---- layers 1,2: in-place leaky(h @ w.T + b); bias in C-init
    #pragma unroll
    for (int li = 0; li < 2; li++) {
        const int poff = 3072 + li * 9216;
        s16x8 A[2][3];
        #pragma unroll
        for (int mf = 0; mf < 2; mf++)
        #pragma unroll
        for (int kt = 0; kt < 3; kt++)
            A[mf][kt] = *(const s16x8*)&h_s[(mbase + mf*16 + lr) * 104 + kt*32 + lg*8];
        f32x4 a2[2][6];
        #pragma unroll
        for (int nt = 0; nt < 6; nt++) {
            float bb = (li == 0) ? b1v[nt] : b2v[nt];
            f32x4 bi = {bb, bb, bb, bb};
            a2[0][nt] = bi; a2[1][nt] = bi;
        }
        #pragma unroll
        for (int nt = 0; nt < 6; nt++)
        #pragma unroll
        for (int kt = 0; kt < 3; kt++) {
            s16x8 B = *(const s16x8*)&wp[poff + (kt*6 + nt) * 512 + l * 8];
            a2[0][nt] = __builtin_amdgcn_mfma_f32_16x16x32_bf16(A[0][kt], B, a2[0][nt], 0, 0, 0);
            a2[1][nt] = __builtin_amdgcn_mfma_f32_16x16x32_bf16(A[1][kt], B, a2[1][nt], 0, 0, 0);
        }
        #pragma unroll
        for (int mf = 0; mf < 2; mf++)
        #pragma unroll
        for (int nt = 0; nt < 6; nt++)
        #pragma unroll
        for (int j = 0; j < 4; j++) {
            float v = a2[mf][nt][j];
            v = fmaxf(v, 0.1f * v);
            h_s[(mbase + mf*16 + lg*4 + j) * 104 + nt*16 + lr] = f2bf(v);
        }
    }

    // ---- layer 3: rad = h @ w3.T -> packed regs only (frag stash after SYNC2)
    uint2 radp[2][6];
    {
        s16x8 A[2][3];
        #pragma unroll
        for (int mf = 0; mf < 2; mf++)
        #pragma unroll
        for (int kt = 0; kt < 3; kt++)
            A[mf][kt] = *(const s16x8*)&h_s[(mbase + mf*16 + lr) * 104 + kt*32 + lg*8];
        f32x4 rad[2][6] = {};
        #pragma unroll
        for (int nt = 0; nt < 6; nt++)
        #pragma unroll
        for (int kt = 0; kt < 3; kt++) {
            s16x8 B = *(const s16x8*)&wp[21504 + (kt*6 + nt) * 512 + l * 8];
            rad[0][nt] = __builtin_amdgcn_mfma_f32_16x16x32_bf16(A[0][kt], B, rad[0][nt], 0, 0, 0);
            rad[1][nt] = __builtin_amdgcn_mfma_f32_16x16x32_bf16(A[1][kt], B, rad[1][nt], 0, 0, 0);
        }
        #pragma unroll
        for (int mf = 0; mf < 2; mf++)
        #pragma unroll
        for (int nt = 0; nt < 6; nt++) {
            unsigned short q0 = f2bf(rad[mf][nt][0]);
            unsigned short q1 = f2bf(rad[mf][nt][1]);
            unsigned short q2 = f2bf(rad[mf][nt][2]);
            unsigned short q3 = f2bf(rad[mf][nt][3]);
            radp[mf][nt].x = (unsigned)q0 | ((unsigned)q1 << 16);
            radp[mf][nt].y = (unsigned)q2 | ((unsigned)q3 << 16);
        }
    }

    __syncthreads();   // SYNC#2: all row-major reads of h done -> overlay allowed

    // ---- rad -> B-fragment-order stash (overlays h_s[0 .. 12288 u16))
    #pragma unroll
    for (int mf = 0; mf < 2; mf++)
    #pragma unroll
    for (int nt = 0; nt < 6; nt++)
        *(uint2*)&h_s[(w*6 + nt) * 512 + ((2*mf + (lg>>1))*16 + lr) * 8 + (lg&1)*4] = radp[mf][nt];

    __syncthreads();   // SYNC#3: rad frags + segid visible

    // ---- segment reduction
    const int nseg = nseg_s;
    if (w == 0) {
        // A_a[seg][feat] = I @ rad
        for (int st = 0; st * 16 < nseg; ++st) {
            const int target = st * 16 + lr;
            f32x4 acc[6] = {};
            #pragma unroll
            for (int kt = 0; kt < 4; kt++) {
                uint2 sid8 = *(const uint2*)&segid_s[kt*32 + 8*lg];
                s16x8 af;
                #pragma unroll
                for (int j = 0; j < 8; j++) {
                    unsigned word = (j < 4) ? sid8.x : sid8.y;
                    int sid = (word >> (8 * (j & 3))) & 255;
                    af[j] = (short)((sid == target) ? 0x3F80 : 0);
                }
                #pragma unroll
                for (int nt = 0; nt < 6; nt++) {
                    s16x8 B = *(const s16x8*)&h_s[(kt*6 + nt) * 512 + l * 8];
                    acc[nt] = __builtin_amdgcn_mfma_f32_16x16x32_bf16(af, B, acc[nt], 0, 0, 0);
                }
            }
            #pragma unroll
            for (int nt = 0; nt < 6; nt++)
            #pragma unroll
            for (int j = 0; j < 4; j++) {
                int g = st*16 + 4*lg + j;
                if (g < nseg) {
                    int node = segnode_s[g];
                    if (node >= 0)
                        unsafeAtomicAdd(&A_a[node*96 + nt*16 + lr], acc[nt][j]);
                }
            }
        }
    } else {
        // S_c[seg][feat] = (I.rv_c) @ rad; stash as A-frags; Ov = S_c @ wv^T
        const int c = w - 1;
        const int scb = 12288 + (w - 1) * 1536;
        for (int st = 0; st * 16 < nseg; ++st) {
            const int target = st * 16 + lr;
            f32x4 acc6[6] = {};
            #pragma unroll
            for (int kt = 0; kt < 4; kt++) {
                uint2 sid8 = *(const uint2*)&segid_s[kt*32 + 8*lg];
                s16x8 rv8 = *(const s16x8*)&rvb_s[c*128 + kt*32 + 8*lg];
                s16x8 af;
                #pragma unroll
                for (int j = 0; j < 8; j++) {
                    unsigned word = (j < 4) ? sid8.x : sid8.y;
                    int sid = (word >> (8 * (j & 3))) & 255;
                    af[j] = (sid == target) ? rv8[j] : (short)0;
                }
                #pragma unroll
                for (int nt = 0; nt < 6; nt++) {
                    s16x8 B = *(const s16x8*)&h_s[(kt*6 + nt) * 512 + l * 8];
                    acc6[nt] = __builtin_amdgcn_mfma_f32_16x16x32_bf16(af, B, acc6[nt], 0, 0, 0);
                }
            }
            // stash S_c (C layout: seg=4lg+j, feat=16nt+lr) into A-frag order:
            // frag ktf=feat>>5; lane'=((feat&31)>>3)*16+seg; elem=feat&7
            #pragma unroll
            for (int nt = 0; nt < 6; nt++) {
                int ktf = nt >> 1;
                int lane2 = ((nt & 1) * 2 + (lr >> 3)) * 16 + 4*lg;
                int a0 = scb + ktf*512 + lane2*8 + (lr & 7);
                h_s[a0]      = f2bf(acc6[nt][0]);
                h_s[a0 + 8]  = f2bf(acc6[nt][1]);
                h_s[a0 + 16] = f2bf(acc6[nt][2]);
                h_s[a0 + 24] = f2bf(acc6[nt][3]);
            }
            // wv GEMM: D[seg][v] = S_c @ wv^T  (wave-private stash; in-wave RAW)
            s16x8 As[3];
            #pragma unroll
            for (int ktf = 0; ktf < 3; ktf++)
                As[ktf] = *(const s16x8*)&h_s[scb + ktf*512 + l*8];
            f32x4 acc2[4] = {};
            #pragma unroll
            for (int vt = 0; vt < 4; vt++)
            #pragma unroll
            for (int ktf = 0; ktf < 3; ktf++) {
                s16x8 B = *(const s16x8*)&wp[30720 + (ktf*4 + vt) * 512 + l * 8];
                acc2[vt] = __builtin_amdgcn_mfma_f32_16x16x32_bf16(As[ktf], B, acc2[vt], 0, 0, 0);
            }
            #pragma unroll
            for (int vt = 0; vt < 4; vt++)
            #pragma unroll
            for (int j = 0; j < 4; j++) {
                int g = st*16 + 4*lg + j;
                if (g < nseg) {
                    int node = segnode_s[g];
                    if (node >= 0)
                        unsafeAtomicAdd(&Ov[node*192 + (vt*16 + lr)*3 + c], acc2[vt][j]);
                }
            }
        }
    }
}

extern "C" void kernel_launch(void* const* d_in, const int* in_sizes, int n_in,
                              void* d_out, int out_size, void* d_ws, size_t ws_size,
                              hipStream_t stream)
{
    const float* r_ij = (const float*)d_in[0];
    const float* w0   = (const float*)d_in[1];
    const float* b0   = (const float*)d_in[2];
    const float* w1   = (const float*)d_in[3];
    const float* b1   = (const float*)d_in[4];
    const float* w2   = (const float*)d_in[5];
    const float* b2   = (const float*)d_in[6];
    const float* w3   = (const float*)d_in[7];
    const float* wv   = (const float*)d_in[8];
    const int*   src  = (const int*)d_in[9];
    const int E = in_sizes[0] / 3;
    const int N = out_size / 288;
    float* A_a = (float*)d_out;
    float* Ov  = A_a + (size_t)N * 96;

    char* wsb = (char*)d_ws;
    unsigned short* wp = (unsigned short*)wsb;                  // 73728 B
    size_t off = 73728;
    int* counts = (int*)(wsb + off);  off += (((size_t)N*4 + 127) & ~127ull);
    int* cursor = (int*)(wsb + off);  off += (((size_t)N*4 + 127) & ~127ull);
    int* bsum   = (int*)(wsb + off);  off += 1024;
    size_t need_rsrt = off + (size_t)E * 16;
    int use_rsrt = (need_rsrt <= ws_size) ? 1 : 0;
    float4* rsrt = (float4*)(wsb + off);
    int* order   = (int*)(wsb + off);
    int* srcs    = (int*)(wsb + off + (((size_t)E*4 + 127) & ~127ull));

    const int nb = (N + 2047) / 2048;

    hipMemsetAsync(d_out, 0, (size_t)out_size * sizeof(float), stream);
    hipMemsetAsync(counts, 0, (size_t)N * 4, stream);

    pack_weights_k<<<(PACK_TOT + 255) / 256, 256, 0, stream>>>(w0, w1, w2, w3, wv, wp);
    hist_k<<<(E + 255) / 256, 256, 0, stream>>>(src, counts, E);
    scan1_k<<<nb, 256, 0, stream>>>(counts, cursor, bsum, N);
    scatter_k<<<(E + 255) / 256, 256, 0, stream>>>(src, r_ij, bsum, cursor,
                                                   order, srcs, rsrt, use_rsrt, nb, E);
    edge_kernel<<<(E + 127) / 128, 256, 0, stream>>>(r_ij, order, srcs, rsrt, use_rsrt,
                                                     wp, b0, b1, b2, A_a, Ov, E);
}

// Round 12
// 246.278 us; speedup vs baseline: 1.1142x; 1.0372x over previous
//
#include <hip/hip_runtime.h>
#include <math.h>

typedef float f32x4 __attribute__((ext_vector_type(4)));
typedef short s16x8 __attribute__((ext_vector_type(8)));

__device__ __forceinline__ unsigned short f2bf(float f) {
    unsigned u = __builtin_bit_cast(unsigned, f);
    u += 0x7fffu + ((u >> 16) & 1u);
    return (unsigned short)(u >> 16);
}

// Pack 4 f32 -> 4 bf16 (round-half-up) in a uint2 via v_perm_b32 (builtin, no asm).
// perm pool: {src1 bytes 0-3 (sel 0-3), src0 bytes 4-7 (sel 4-7)}.
// dst = [u1.b3 u1.b2 u0.b3 u0.b2] -> sel 0x07060302 with (src0=u1, src1=u0).
__device__ __forceinline__ uint2 pack4(float q0, float q1, float q2, float q3) {
    unsigned u0 = __builtin_bit_cast(unsigned, q0) + 0x8000u;
    unsigned u1 = __builtin_bit_cast(unsigned, q1) + 0x8000u;
    unsigned u2 = __builtin_bit_cast(unsigned, q2) + 0x8000u;
    unsigned u3 = __builtin_bit_cast(unsigned, q3) + 0x8000u;
    uint2 r;
    r.x = __builtin_amdgcn_perm(u1, u0, 0x07060302);
    r.y = __builtin_amdgcn_perm(u3, u2, 0x07060302);
    return r;
}

// Bijective XCD-chunking swizzle (kept from r11; harmless).
__device__ __forceinline__ int xcd_swizzle(int b, int nwg) {
    int q = nwg >> 3, r = nwg & 7;
    int xcd = b & 7, slot = b >> 3;
    int base = (xcd < r) ? xcd * (q + 1) : r * (q + 1) + (xcd - r) * q;
    return base + slot;
}

// ---------------- weight packing ----------------
// Frag (kt,nt): lane l elem j holds W[16nt+(l&15)][32kt+8*(l>>4)+j].
// Serves as MFMA B-frag (W^T as B) AND as A-frag (W rows as A) unchanged.
#define PACK_TOT 36864

__global__ __launch_bounds__(256) void pack_weights_k(
    const float* __restrict__ w0, const float* __restrict__ w1,
    const float* __restrict__ w2, const float* __restrict__ w3,
    const float* __restrict__ wv, unsigned short* __restrict__ dst)
{
    int idx = blockIdx.x * 256 + threadIdx.x;
    if (idx >= PACK_TOT) return;
    const float* W; int inF, ntiles, off;
    if (idx < 3072)       { W = w0; inF = 8;  ntiles = 6; off = 0; }
    else if (idx < 12288) { W = w1; inF = 96; ntiles = 6; off = 3072; }
    else if (idx < 21504) { W = w2; inF = 96; ntiles = 6; off = 12288; }
    else if (idx < 30720) { W = w3; inF = 96; ntiles = 6; off = 21504; }
    else                  { W = wv; inF = 96; ntiles = 4; off = 30720; }
    int r  = idx - off;
    int fi = r >> 9;
    int wi = r & 511;
    int l = wi >> 3, j = wi & 7;
    int kt = fi / ntiles, nt = fi - kt * ntiles;
    int n = nt * 16 + (l & 15);
    int k = kt * 32 + ((l >> 4) << 3) + j;
    float v = (k < inF) ? W[n * inF + k] : 0.0f;
    dst[idx] = f2bf(v);
}

// ---------------- CSR build ----------------
__global__ __launch_bounds__(256) void hist_k(const int* __restrict__ src,
                                              int* __restrict__ counts, int E)
{
    int e = blockIdx.x * 256 + threadIdx.x;
    if (e < E) atomicAdd(&counts[src[e]], 1);
}

__global__ __launch_bounds__(256) void scan1_k(const int* __restrict__ counts,
                                               int* __restrict__ cursor,
                                               int* __restrict__ bsum, int N)
{
    __shared__ int wsum_s[4];
    int b = blockIdx.x, t = threadIdx.x, lane = t & 63, wid = t >> 6;
    int i0 = b * 2048 + t * 8;
    int v[8]; int s = 0;
    #pragma unroll
    for (int j = 0; j < 8; j++) { int i = i0 + j; v[j] = (i < N) ? counts[i] : 0; s += v[j]; }
    int inc = s;
    #pragma unroll
    for (int d = 1; d < 64; d <<= 1) { int o = __shfl_up(inc, d, 64); if (lane >= d) inc += o; }
    if (lane == 63) wsum_s[wid] = inc;
    __syncthreads();
    int wb = 0;
    for (int k = 0; k < wid; k++) wb += wsum_s[k];
    int run = wb + inc - s;
    #pragma unroll
    for (int j = 0; j < 8; j++) { int i = i0 + j; if (i < N) cursor[i] = run; run += v[j]; }
    if (t == 255) bsum[b] = wb + inc;
}

// scatter with inline chunk-total prefix (r11-proven)
__global__ __launch_bounds__(256) void scatter_k(const int* __restrict__ src,
                                                 const float* __restrict__ r_ij,
                                                 const int* __restrict__ bsum,
                                                 int* __restrict__ cursor,
                                                 int* __restrict__ order,
                                                 int* __restrict__ srcs,
                                                 float4* __restrict__ rsrt,
                                                 int use_rsrt, int nb, int E)
{
    __shared__ int pre_s[256];
    int t = threadIdx.x;
    if (t < 64) {
        int carry = 0;
        for (int base = 0; base < nb; base += 64) {
            int i = base + t;
            int v = (i < nb) ? bsum[i] : 0;
            int inc = v;
            #pragma unroll
            for (int d = 1; d < 64; d <<= 1) {
                int o = __shfl_up(inc, d, 64);
                if (t >= d) inc += o;
            }
            if (i < nb) pre_s[i] = carry + inc - v;
            carry += __shfl(inc, 63);
        }
    }
    __syncthreads();
    int e = blockIdx.x * 256 + t;
    if (e < E) {
        int s = src[e];
        int p = pre_s[s >> 11] + atomicAdd(&cursor[s], 1);
        if (use_rsrt) {
            rsrt[p] = make_float4(r_ij[3*e], r_ij[3*e+1], r_ij[3*e+2], __int_as_float(s));
        } else {
            order[p] = e;
            srcs[p] = s;
        }
    }
}

// ---------------- fused edge kernel ----------------
// r11 structure; layers 0-2 computed in SWAPPED orientation:
//   D[feat][edge] = mfma(A=W_frag(wp, unchanged), B=h_frag(same b128 LDS read))
// so each thread's 4 acc values = 4 consecutive feats of 1 edge -> single uint2
// epilogue write (48 scalar ds_write_u16 -> 12 ds_write_b64 per layer).
// Layer 3 + segment reduction keep the r11 orientation (already wide).
__global__ __launch_bounds__(256, 3) void edge_kernel(
    const float* __restrict__ r_ij,
    const int* __restrict__ order, const int* __restrict__ srcs,
    const float4* __restrict__ rsrt, int use_rsrt,
    const unsigned short* __restrict__ wp,
    const float* __restrict__ b0, const float* __restrict__ b1, const float* __restrict__ b2,
    float* __restrict__ A_a, float* __restrict__ Ov, int E)
{
    // [0..13312): row-major MLP buffer (stride 104, cols 96..103 = enc)
    // after SYNC2 overlay: [0..12288) = 24 rad B-frags (512 u16 each)
    // [12288..16896): per-wave S_c A-frag scratch for waves 1..3
    __shared__ unsigned short h_s[16896];
    __shared__ unsigned short rvb_s[3 * 128];      // bf16 rv, [c][row]
    __shared__ unsigned char  segid_s[128];
    __shared__ int  segnode_s[128];
    __shared__ int  src_s[128];
    __shared__ int  nseg_s;

    const int tid = threadIdx.x;
    const int w  = tid >> 6;
    const int l  = tid & 63;
    const int e0 = xcd_swizzle(blockIdx.x, gridDim.x) * 128;
    const int lr = l & 15;
    const int lg = l >> 4;
    const int mbase = w * 32;

    // ---- stage per-edge scalars (coalesced float4 fast path)
    if (l < 32) {
        const int ml = mbase + l;
        const int pos = e0 + ml;
        float x = 0.f, y = 0.f, z = 0.f; int s = -1;
        if (pos < E) {
            if (use_rsrt) {
                float4 v4 = rsrt[pos];
                x = v4.x; y = v4.y; z = v4.z; s = __float_as_int(v4.w);
            } else {
                int e = order[pos];
                s = srcs[pos];
                x = r_ij[3*e]; y = r_ij[3*e+1]; z = r_ij[3*e+2];
            }
        }
        float r = sqrtf(x*x + y*y + z*z);
        float u = r * 4.0f;               // r * 8/R0, R0=2
        s16x8 ev;
        #pragma unroll
        for (int k = 0; k < 8; k++) {
            float t = fmaxf(1.0f - fabsf(u - (float)k), 0.0f);
            ev[k] = (short)f2bf((s >= 0) ? t : 0.0f);
        }
        *(s16x8*)&h_s[ml * 104 + 96] = ev;     // enc into pad cols
        float nn = 3.5f * r;
        float sc = (s >= 0) ? (3.5f * tanhf(nn) / fmaxf(nn, 1e-12f)) : 0.0f;
        rvb_s[0*128 + ml] = f2bf(x * sc);
        rvb_s[1*128 + ml] = f2bf(y * sc);
        rvb_s[2*128 + ml] = f2bf(z * sc);
        src_s[ml] = s;
    }
    __syncthreads();   // SYNC#1: src_s/enc visible

    // ---- wave 0: build segid / segnode / nseg (ballot-based prefix)
    if (w == 0) {
        int i = l;
        int sA = src_s[i];
        bool fA = (i == 0) || (sA != src_s[i - 1]);
        unsigned long long mA = __ballot(fA);
        unsigned long long maskA = (~0ull) >> (63 - i);
        int incA = (int)__popcll(mA & maskA);
        segid_s[i] = (unsigned char)(incA - 1);
        if (fA) segnode_s[incA - 1] = sA;
        int totA = (int)__popcll(mA);
        int jrow = 64 + i;
        int sB = src_s[jrow];
        bool fB = (sB != src_s[jrow - 1]);
        unsigned long long mB = __ballot(fB);
        int incB = (int)__popcll(mB & maskA);
        segid_s[jrow] = (unsigned char)(totA + incB - 1);
        if (fB) segnode_s[totA + incB - 1] = sB;
        if (i == 63) nseg_s = totA + (int)__popcll(mB);
    }

    // ---- biases as float4 per (nt, lg): feat = nt*16 + lg*4 + jj  (swapped D layout)
    f32x4 b0v4[6], b1v4[6], b2v4[6];
    #pragma unroll
    for (int nt = 0; nt < 6; nt++) {
        float4 t0 = *(const float4*)&b0[nt*16 + lg*4];
        float4 t1 = *(const float4*)&b1[nt*16 + lg*4];
        float4 t2 = *(const float4*)&b2[nt*16 + lg*4];
        b0v4[nt] = (f32x4){t0.x, t0.y, t0.z, t0.w};
        b1v4[nt] = (f32x4){t1.x, t1.y, t1.z, t1.w};
        b2v4[nt] = (f32x4){t2.x, t2.y, t2.z, t2.w};
    }

    // ---- layer 0 (swapped): D[feat][edge] = w0_frag x enc_frag + b0
    // enc B-frag: lanes l<16 load 8 valid k (cols 96..103); lanes >=16 MUST be
    // zeroed (uninit LDS could be NaN; 0 x NaN = NaN even though wp pads k>=8).
    {
        s16x8 hb[2];
        #pragma unroll
        for (int mf = 0; mf < 2; mf++) {
            s16x8 a = {0,0,0,0,0,0,0,0};
            if (l < 16) a = *(const s16x8*)&h_s[(mbase + mf*16 + lr) * 104 + 96];
            hb[mf] = a;
        }
        f32x4 acc[2][6];
        #pragma unroll
        for (int nt = 0; nt < 6; nt++) {
            s16x8 Wf = *(const s16x8*)&wp[nt * 512 + l * 8];
            acc[0][nt] = __builtin_amdgcn_mfma_f32_16x16x32_bf16(Wf, hb[0], b0v4[nt], 0, 0, 0);
            acc[1][nt] = __builtin_amdgcn_mfma_f32_16x16x32_bf16(Wf, hb[1], b0v4[nt], 0, 0, 0);
        }
        #pragma unroll
        for (int mf = 0; mf < 2; mf++)
        #pragma unroll
        for (int nt = 0; nt < 6; nt++)
            *(uint2*)&h_s[(mbase + mf*16 + lr) * 104 + nt*16 + lg*4] =
                pack4(acc[mf][nt][0], acc[mf][nt][1], acc[mf][nt][2], acc[mf][nt][3]);
    }

    // ---- layers 1,2 (swapped): in-place leaky(W x h + b); b64 epilogue
    #pragma unroll
    for (int li = 0; li < 2; li++) {
        const int poff = 3072 + li * 9216;
        s16x8 A[2][3];
        #pragma unroll
        for (int mf = 0; mf < 2; mf++)
        #pragma unroll
        for (int kt = 0; kt < 3; kt++)
            A[mf][kt] = *(const s16x8*)&h_s[(mbase + mf*16 + lr) * 104 + kt*32 + lg*8];
        f32x4 a2[2][6];
        #pragma unroll
        for (int nt = 0; nt < 6; nt++) {
            f32x4 bi = (li == 0) ? b1v4[nt] : b2v4[nt];
            a2[0][nt] = bi; a2[1][nt] = bi;
        }
        #pragma unroll
        for (int nt = 0; nt < 6; nt++)
        #pragma unroll
        for (int kt = 0; kt < 3; kt++) {
            s16x8 Wf = *(const s16x8*)&wp[poff + (kt*6 + nt) * 512 + l * 8];
            a2[0][nt] = __builtin_amdgcn_mfma_f32_16x16x32_bf16(Wf, A[0][kt], a2[0][nt], 0, 0, 0);
            a2[1][nt] = __builtin_amdgcn_mfma_f32_16x16x32_bf16(Wf, A[1][kt], a2[1][nt], 0, 0, 0);
        }
        #pragma unroll
        for (int mf = 0; mf < 2; mf++)
        #pragma unroll
        for (int nt = 0; nt < 6; nt++) {
            float q0 = a2[mf][nt][0], q1 = a2[mf][nt][1];
            float q2 = a2[mf][nt][2], q3 = a2[mf][nt][3];
            q0 = fmaxf(q0, 0.1f*q0); q1 = fmaxf(q1, 0.1f*q1);
            q2 = fmaxf(q2, 0.1f*q2); q3 = fmaxf(q3, 0.1f*q3);
            *(uint2*)&h_s[(mbase + mf*16 + lr) * 104 + nt*16 + lg*4] = pack4(q0, q1, q2, q3);
        }
    }

    // ---- layer 3 (old orientation): rad = h @ w3.T -> packed regs for frag stash
    uint2 radp[2][6];
    {
        s16x8 A[2][3];
        #pragma unroll
        for (int mf = 0; mf < 2; mf++)
        #pragma unroll
        for (int kt = 0; kt < 3; kt++)
            A[mf][kt] = *(const s16x8*)&h_s[(mbase + mf*16 + lr) * 104 + kt*32 + lg*8];
        f32x4 rad[2][6] = {};
        #pragma unroll
        for (int nt = 0; nt < 6; nt++)
        #pragma unroll
        for (int kt = 0; kt < 3; kt++) {
            s16x8 B = *(const s16x8*)&wp[21504 + (kt*6 + nt) * 512 + l * 8];
            rad[0][nt] = __builtin_amdgcn_mfma_f32_16x16x32_bf16(A[0][kt], B, rad[0][nt], 0, 0, 0);
            rad[1][nt] = __builtin_amdgcn_mfma_f32_16x16x32_bf16(A[1][kt], B, rad[1][nt], 0, 0, 0);
        }
        #pragma unroll
        for (int mf = 0; mf < 2; mf++)
        #pragma unroll
        for (int nt = 0; nt < 6; nt++)
            radp[mf][nt] = pack4(rad[mf][nt][0], rad[mf][nt][1], rad[mf][nt][2], rad[mf][nt][3]);
    }

    __syncthreads();   // SYNC#2: all row-major reads of h done -> overlay allowed

    // ---- rad -> B-fragment-order stash (overlays h_s[0 .. 12288 u16))
    #pragma unroll
    for (int mf = 0; mf < 2; mf++)
    #pragma unroll
    for (int nt = 0; nt < 6; nt++)
        *(uint2*)&h_s[(w*6 + nt) * 512 + ((2*mf + (lg>>1))*16 + lr) * 8 + (lg&1)*4] = radp[mf][nt];

    __syncthreads();   // SYNC#3: rad frags + segid visible

    // ---- segment reduction (unchanged r11)
    const int nseg = nseg_s;
    if (w == 0) {
        // A_a[seg][feat] = I @ rad
        for (int st = 0; st * 16 < nseg; ++st) {
            const int target = st * 16 + lr;
            f32x4 acc[6] = {};
            #pragma unroll
            for (int kt = 0; kt < 4; kt++) {
                uint2 sid8 = *(const uint2*)&segid_s[kt*32 + 8*lg];
                s16x8 af;
                #pragma unroll
                for (int j = 0; j < 8; j++) {
                    unsigned word = (j < 4) ? sid8.x : sid8.y;
                    int sid = (word >> (8 * (j & 3))) & 255;
                    af[j] = (short)((sid == target) ? 0x3F80 : 0);
                }
                #pragma unroll
                for (int nt = 0; nt < 6; nt++) {
                    s16x8 B = *(const s16x8*)&h_s[(kt*6 + nt) * 512 + l * 8];
                    acc[nt] = __builtin_amdgcn_mfma_f32_16x16x32_bf16(af, B, acc[nt], 0, 0, 0);
                }
            }
            #pragma unroll
            for (int nt = 0; nt < 6; nt++)
            #pragma unroll
            for (int j = 0; j < 4; j++) {
                int g = st*16 + 4*lg + j;
                if (g < nseg) {
                    int node = segnode_s[g];
                    if (node >= 0)
                        unsafeAtomicAdd(&A_a[node*96 + nt*16 + lr], acc[nt][j]);
                }
            }
        }
    } else {
        // S_c[seg][feat] = (I.rv_c) @ rad; stash as A-frags; Ov = S_c @ wv^T
        const int c = w - 1;
        const int scb = 12288 + (w - 1) * 1536;
        for (int st = 0; st * 16 < nseg; ++st) {
            const int target = st * 16 + lr;
            f32x4 acc6[6] = {};
            #pragma unroll
            for (int kt = 0; kt < 4; kt++) {
                uint2 sid8 = *(const uint2*)&segid_s[kt*32 + 8*lg];
                s16x8 rv8 = *(const s16x8*)&rvb_s[c*128 + kt*32 + 8*lg];
                s16x8 af;
                #pragma unroll
                for (int j = 0; j < 8; j++) {
                    unsigned word = (j < 4) ? sid8.x : sid8.y;
                    int sid = (word >> (8 * (j & 3))) & 255;
                    af[j] = (sid == target) ? rv8[j] : (short)0;
                }
                #pragma unroll
                for (int nt = 0; nt < 6; nt++) {
                    s16x8 B = *(const s16x8*)&h_s[(kt*6 + nt) * 512 + l * 8];
                    acc6[nt] = __builtin_amdgcn_mfma_f32_16x16x32_bf16(af, B, acc6[nt], 0, 0, 0);
                }
            }
            // stash S_c (C layout: seg=4lg+j, feat=16nt+lr) into A-frag order
            #pragma unroll
            for (int nt = 0; nt < 6; nt++) {
                int ktf = nt >> 1;
                int lane2 = ((nt & 1) * 2 + (lr >> 3)) * 16 + 4*lg;
                int a0 = scb + ktf*512 + lane2*8 + (lr & 7);
                h_s[a0]      = f2bf(acc6[nt][0]);
                h_s[a0 + 8]  = f2bf(acc6[nt][1]);
                h_s[a0 + 16] = f2bf(acc6[nt][2]);
                h_s[a0 + 24] = f2bf(acc6[nt][3]);
            }
            // wv GEMM: D[seg][v] = S_c @ wv^T  (wave-private stash; in-wave RAW)
            s16x8 As[3];
            #pragma unroll
            for (int ktf = 0; ktf < 3; ktf++)
                As[ktf] = *(const s16x8*)&h_s[scb + ktf*512 + l*8];
            f32x4 acc2[4] = {};
            #pragma unroll
            for (int vt = 0; vt < 4; vt++)
            #pragma unroll
            for (int ktf = 0; ktf < 3; ktf++) {
                s16x8 B = *(const s16x8*)&wp[30720 + (ktf*4 + vt) * 512 + l * 8];
                acc2[vt] = __builtin_amdgcn_mfma_f32_16x16x32_bf16(As[ktf], B, acc2[vt], 0, 0, 0);
            }
            #pragma unroll
            for (int vt = 0; vt < 4; vt++)
            #pragma unroll
            for (int j = 0; j < 4; j++) {
                int g = st*16 + 4*lg + j;
                if (g < nseg) {
                    int node = segnode_s[g];
                    if (node >= 0)
                        unsafeAtomicAdd(&Ov[node*192 + (vt*16 + lr)*3 + c], acc2[vt][j]);
                }
            }
        }
    }
}

extern "C" void kernel_launch(void* const* d_in, const int* in_sizes, int n_in,
                              void* d_out, int out_size, void* d_ws, size_t ws_size,
                              hipStream_t stream)
{
    const float* r_ij = (const float*)d_in[0];
    const float* w0   = (const float*)d_in[1];
    const float* b0   = (const float*)d_in[2];
    const float* w1   = (const float*)d_in[3];
    const float* b1   = (const float*)d_in[4];
    const float* w2   = (const float*)d_in[5];
    const float* b2   = (const float*)d_in[6];
    const float* w3   = (const float*)d_in[7];
    const float* wv   = (const float*)d_in[8];
    const int*   src  = (const int*)d_in[9];
    const int E = in_sizes[0] / 3;
    const int N = out_size / 288;
    float* A_a = (float*)d_out;
    float* Ov  = A_a + (size_t)N * 96;

    char* wsb = (char*)d_ws;
    unsigned short* wp = (unsigned short*)wsb;                  // 73728 B
    size_t off = 73728;
    int* counts = (int*)(wsb + off);  off += (((size_t)N*4 + 127) & ~127ull);
    int* cursor = (int*)(wsb + off);  off += (((size_t)N*4 + 127) & ~127ull);
    int* bsum   = (int*)(wsb + off);  off += 1024;
    size_t need_rsrt = off + (size_t)E * 16;
    int use_rsrt = (need_rsrt <= ws_size) ? 1 : 0;
    float4* rsrt = (float4*)(wsb + off);
    int* order   = (int*)(wsb + off);
    int* srcs    = (int*)(wsb + off + (((size_t)E*4 + 127) & ~127ull));

    const int nb = (N + 2047) / 2048;

    hipMemsetAsync(d_out, 0, (size_t)out_size * sizeof(float), stream);
    hipMemsetAsync(counts, 0, (size_t)N * 4, stream);

    pack_weights_k<<<(PACK_TOT + 255) / 256, 256, 0, stream>>>(w0, w1, w2, w3, wv, wp);
    hist_k<<<(E + 255) / 256, 256, 0, stream>>>(src, counts, E);
    scan1_k<<<nb, 256, 0, stream>>>(counts, cursor, bsum, N);
    scatter_k<<<(E + 255) / 256, 256, 0, stream>>>(src, r_ij, bsum, cursor,
                                                   order, srcs, rsrt, use_rsrt, nb, E);
    edge_kernel<<<(E + 127) / 128, 256, 0, stream>>>(r_ij, order, srcs, rsrt, use_rsrt,
                                                     wp, b0, b1, b2, A_a, Ov, E);
}

// Round 13
// 238.009 us; speedup vs baseline: 1.1529x; 1.0347x over previous
//
#include <hip/hip_runtime.h>
#include <math.h>

typedef float f32x4 __attribute__((ext_vector_type(4)));
typedef short s16x8 __attribute__((ext_vector_type(8)));

__device__ __forceinline__ unsigned short f2bf(float f) {
    unsigned u = __builtin_bit_cast(unsigned, f);
    u += 0x7fffu + ((u >> 16) & 1u);
    return (unsigned short)(u >> 16);
}

// Pack 4 f32 -> 4 bf16 (round-half-up) via v_perm_b32 (builtin, no asm).
__device__ __forceinline__ uint2 pack4(float q0, float q1, float q2, float q3) {
    unsigned u0 = __builtin_bit_cast(unsigned, q0) + 0x8000u;
    unsigned u1 = __builtin_bit_cast(unsigned, q1) + 0x8000u;
    unsigned u2 = __builtin_bit_cast(unsigned, q2) + 0x8000u;
    unsigned u3 = __builtin_bit_cast(unsigned, q3) + 0x8000u;
    uint2 r;
    r.x = __builtin_amdgcn_perm(u1, u0, 0x07060302);
    r.y = __builtin_amdgcn_perm(u3, u2, 0x07060302);
    return r;
}

// Bijective XCD-chunking swizzle (kept; harmless).
__device__ __forceinline__ int xcd_swizzle(int b, int nwg) {
    int q = nwg >> 3, r = nwg & 7;
    int xcd = b & 7, slot = b >> 3;
    int base = (xcd < r) ? xcd * (q + 1) : r * (q + 1) + (xcd - r) * q;
    return base + slot;
}

// ---------------- weight packing (+ fused counts zeroing) ----------------
// Frag (kt,nt): lane l elem j holds W[16nt+(l&15)][32kt+8*(l>>4)+j].
#define PACK_TOT 36864

__global__ __launch_bounds__(256) void pack_weights_k(
    const float* __restrict__ w0, const float* __restrict__ w1,
    const float* __restrict__ w2, const float* __restrict__ w3,
    const float* __restrict__ wv, unsigned short* __restrict__ dst,
    int* __restrict__ counts, int N)
{
    int idx = blockIdx.x * 256 + threadIdx.x;
    int stride = gridDim.x * 256;
    for (int i = idx; i < N; i += stride) counts[i] = 0;   // replaces memset(counts)
    if (idx >= PACK_TOT) return;
    const float* W; int inF, ntiles, off;
    if (idx < 3072)       { W = w0; inF = 8;  ntiles = 6; off = 0; }
    else if (idx < 12288) { W = w1; inF = 96; ntiles = 6; off = 3072; }
    else if (idx < 21504) { W = w2; inF = 96; ntiles = 6; off = 12288; }
    else if (idx < 30720) { W = w3; inF = 96; ntiles = 6; off = 21504; }
    else                  { W = wv; inF = 96; ntiles = 4; off = 30720; }
    int r  = idx - off;
    int fi = r >> 9;
    int wi = r & 511;
    int l = wi >> 3, j = wi & 7;
    int kt = fi / ntiles, nt = fi - kt * ntiles;
    int n = nt * 16 + (l & 15);
    int k = kt * 32 + ((l >> 4) << 3) + j;
    float v = (k < inF) ? W[n * inF + k] : 0.0f;
    dst[idx] = f2bf(v);
}

// ---------------- CSR build (+ fused d_out zeroing) ----------------
__global__ __launch_bounds__(256) void hist_k(const int* __restrict__ src,
                                              int* __restrict__ counts,
                                              float4* __restrict__ dz, long nz,
                                              int E)
{
    long tid = (long)blockIdx.x * 256 + threadIdx.x;
    long stride = (long)gridDim.x * 256;
    float4 z4 = make_float4(0.f, 0.f, 0.f, 0.f);
    for (long i = tid; i < nz; i += stride) dz[i] = z4;     // replaces memset(d_out)
    int e = blockIdx.x * 256 + threadIdx.x;
    if (e < E) atomicAdd(&counts[src[e]], 1);
}

__global__ __launch_bounds__(256) void scan1_k(const int* __restrict__ counts,
                                               int* __restrict__ cursor,
                                               int* __restrict__ bsum, int N)
{
    __shared__ int wsum_s[4];
    int b = blockIdx.x, t = threadIdx.x, lane = t & 63, wid = t >> 6;
    int i0 = b * 2048 + t * 8;
    int v[8]; int s = 0;
    #pragma unroll
    for (int j = 0; j < 8; j++) { int i = i0 + j; v[j] = (i < N) ? counts[i] : 0; s += v[j]; }
    int inc = s;
    #pragma unroll
    for (int d = 1; d < 64; d <<= 1) { int o = __shfl_up(inc, d, 64); if (lane >= d) inc += o; }
    if (lane == 63) wsum_s[wid] = inc;
    __syncthreads();
    int wb = 0;
    for (int k = 0; k < wid; k++) wb += wsum_s[k];
    int run = wb + inc - s;
    #pragma unroll
    for (int j = 0; j < 8; j++) { int i = i0 + j; if (i < N) cursor[i] = run; run += v[j]; }
    if (t == 255) bsum[b] = wb + inc;
}

// scatter with inline chunk-total prefix (r11-proven)
__global__ __launch_bounds__(256) void scatter_k(const int* __restrict__ src,
                                                 const float* __restrict__ r_ij,
                                                 const int* __restrict__ bsum,
                                                 int* __restrict__ cursor,
                                                 int* __restrict__ order,
                                                 int* __restrict__ srcs,
                                                 float4* __restrict__ rsrt,
                                                 int use_rsrt, int nb, int E)
{
    __shared__ int pre_s[256];
    int t = threadIdx.x;
    if (t < 64) {
        int carry = 0;
        for (int base = 0; base < nb; base += 64) {
            int i = base + t;
            int v = (i < nb) ? bsum[i] : 0;
            int inc = v;
            #pragma unroll
            for (int d = 1; d < 64; d <<= 1) {
                int o = __shfl_up(inc, d, 64);
                if (t >= d) inc += o;
            }
            if (i < nb) pre_s[i] = carry + inc - v;
            carry += __shfl(inc, 63);
        }
    }
    __syncthreads();
    int e = blockIdx.x * 256 + t;
    if (e < E) {
        int s = src[e];
        int p = pre_s[s >> 11] + atomicAdd(&cursor[s], 1);
        if (use_rsrt) {
            rsrt[p] = make_float4(r_ij[3*e], r_ij[3*e+1], r_ij[3*e+2], __int_as_float(s));
        } else {
            order[p] = e;
            srcs[p] = s;
        }
    }
}

// ---------------- fused edge kernel (r12 body; rsrt load is non-temporal) ----
__global__ __launch_bounds__(256, 3) void edge_kernel(
    const float* __restrict__ r_ij,
    const int* __restrict__ order, const int* __restrict__ srcs,
    const float4* __restrict__ rsrt, int use_rsrt,
    const unsigned short* __restrict__ wp,
    const float* __restrict__ b0, const float* __restrict__ b1, const float* __restrict__ b2,
    float* __restrict__ A_a, float* __restrict__ Ov, int E)
{
    __shared__ unsigned short h_s[16896];
    __shared__ unsigned short rvb_s[3 * 128];      // bf16 rv, [c][row]
    __shared__ unsigned char  segid_s[128];
    __shared__ int  segnode_s[128];
    __shared__ int  src_s[128];
    __shared__ int  nseg_s;

    const int tid = threadIdx.x;
    const int w  = tid >> 6;
    const int l  = tid & 63;
    const int e0 = xcd_swizzle(blockIdx.x, gridDim.x) * 128;
    const int lr = l & 15;
    const int lg = l >> 4;
    const int mbase = w * 32;

    // ---- stage per-edge scalars (NT streaming load: rsrt is read-once; keep
    // it out of L2 so the atomic output lines stay resident — r9/r11 showed
    // L2 capacity is the binding constraint)
    if (l < 32) {
        const int ml = mbase + l;
        const int pos = e0 + ml;
        float x = 0.f, y = 0.f, z = 0.f; int s = -1;
        if (pos < E) {
            if (use_rsrt) {
                f32x4 t4 = __builtin_nontemporal_load((const f32x4*)&rsrt[pos]);
                x = t4[0]; y = t4[1]; z = t4[2]; s = __float_as_int(t4[3]);
            } else {
                int e = order[pos];
                s = srcs[pos];
                x = r_ij[3*e]; y = r_ij[3*e+1]; z = r_ij[3*e+2];
            }
        }
        float r = sqrtf(x*x + y*y + z*z);
        float u = r * 4.0f;               // r * 8/R0, R0=2
        s16x8 ev;
        #pragma unroll
        for (int k = 0; k < 8; k++) {
            float t = fmaxf(1.0f - fabsf(u - (float)k), 0.0f);
            ev[k] = (short)f2bf((s >= 0) ? t : 0.0f);
        }
        *(s16x8*)&h_s[ml * 104 + 96] = ev;     // enc into pad cols
        float nn = 3.5f * r;
        float sc = (s >= 0) ? (3.5f * tanhf(nn) / fmaxf(nn, 1e-12f)) : 0.0f;
        rvb_s[0*128 + ml] = f2bf(x * sc);
        rvb_s[1*128 + ml] = f2bf(y * sc);
        rvb_s[2*128 + ml] = f2bf(z * sc);
        src_s[ml] = s;
    }
    __syncthreads();   // SYNC#1: src_s/enc visible

    // ---- wave 0: build segid / segnode / nseg (ballot-based prefix)
    if (w == 0) {
        int i = l;
        int sA = src_s[i];
        bool fA = (i == 0) || (sA != src_s[i - 1]);
        unsigned long long mA = __ballot(fA);
        unsigned long long maskA = (~0ull) >> (63 - i);
        int incA = (int)__popcll(mA & maskA);
        segid_s[i] = (unsigned char)(incA - 1);
        if (fA) segnode_s[incA - 1] = sA;
        int totA = (int)__popcll(mA);
        int jrow = 64 + i;
        int sB = src_s[jrow];
        bool fB = (sB != src_s[jrow - 1]);
        unsigned long long mB = __ballot(fB);
        int incB = (int)__popcll(mB & maskA);
        segid_s[jrow] = (unsigned char)(totA + incB - 1);
        if (fB) segnode_s[totA + incB - 1] = sB;
        if (i == 63) nseg_s = totA + (int)__popcll(mB);
    }

    // ---- biases as float4 per (nt, lg): feat = nt*16 + lg*4 + jj (swapped D)
    f32x4 b0v4[6], b1v4[6], b2v4[6];
    #pragma unroll
    for (int nt = 0; nt < 6; nt++) {
        float4 t0 = *(const float4*)&b0[nt*16 + lg*4];
        float4 t1 = *(const float4*)&b1[nt*16 + lg*4];
        float4 t2 = *(const float4*)&b2[nt*16 + lg*4];
        b0v4[nt] = (f32x4){t0.x, t0.y, t0.z, t0.w};
        b1v4[nt] = (f32x4){t1.x, t1.y, t1.z, t1.w};
        b2v4[nt] = (f32x4){t2.x, t2.y, t2.z, t2.w};
    }

    // ---- layer 0 (swapped): D[feat][edge] = w0_frag x enc_frag + b0
    {
        s16x8 hb[2];
        #pragma unroll
        for (int mf = 0; mf < 2; mf++) {
            s16x8 a = {0,0,0,0,0,0,0,0};
            if (l < 16) a = *(const s16x8*)&h_s[(mbase + mf*16 + lr) * 104 + 96];
            hb[mf] = a;
        }
        f32x4 acc[2][6];
        #pragma unroll
        for (int nt = 0; nt < 6; nt++) {
            s16x8 Wf = *(const s16x8*)&wp[nt * 512 + l * 8];
            acc[0][nt] = __builtin_amdgcn_mfma_f32_16x16x32_bf16(Wf, hb[0], b0v4[nt], 0, 0, 0);
            acc[1][nt] = __builtin_amdgcn_mfma_f32_16x16x32_bf16(Wf, hb[1], b0v4[nt], 0, 0, 0);
        }
        #pragma unroll
        for (int mf = 0; mf < 2; mf++)
        #pragma unroll
        for (int nt = 0; nt < 6; nt++)
            *(uint2*)&h_s[(mbase + mf*16 + lr) * 104 + nt*16 + lg*4] =
                pack4(acc[mf][nt][0], acc[mf][nt][1], acc[mf][nt][2], acc[mf][nt][3]);
    }

    // ---- layers 1,2 (swapped): in-place leaky(W x h + b); b64 epilogue
    #pragma unroll
    for (int li = 0; li < 2; li++) {
        const int poff = 3072 + li * 9216;
        s16x8 A[2][3];
        #pragma unroll
        for (int mf = 0; mf < 2; mf++)
        #pragma unroll
        for (int kt = 0; kt < 3; kt++)
            A[mf][kt] = *(const s16x8*)&h_s[(mbase + mf*16 + lr) * 104 + kt*32 + lg*8];
        f32x4 a2[2][6];
        #pragma unroll
        for (int nt = 0; nt < 6; nt++) {
            f32x4 bi = (li == 0) ? b1v4[nt] : b2v4[nt];
            a2[0][nt] = bi; a2[1][nt] = bi;
        }
        #pragma unroll
        for (int nt = 0; nt < 6; nt++)
        #pragma unroll
        for (int kt = 0; kt < 3; kt++) {
            s16x8 Wf = *(const s16x8*)&wp[poff + (kt*6 + nt) * 512 + l * 8];
            a2[0][nt] = __builtin_amdgcn_mfma_f32_16x16x32_bf16(Wf, A[0][kt], a2[0][nt], 0, 0, 0);
            a2[1][nt] = __builtin_amdgcn_mfma_f32_16x16x32_bf16(Wf, A[1][kt], a2[1][nt], 0, 0, 0);
        }
        #pragma unroll
        for (int mf = 0; mf < 2; mf++)
        #pragma unroll
        for (int nt = 0; nt < 6; nt++) {
            float q0 = a2[mf][nt][0], q1 = a2[mf][nt][1];
            float q2 = a2[mf][nt][2], q3 = a2[mf][nt][3];
            q0 = fmaxf(q0, 0.1f*q0); q1 = fmaxf(q1, 0.1f*q1);
            q2 = fmaxf(q2, 0.1f*q2); q3 = fmaxf(q3, 0.1f*q3);
            *(uint2*)&h_s[(mbase + mf*16 + lr) * 104 + nt*16 + lg*4] = pack4(q0, q1, q2, q3);
        }
    }

    // ---- layer 3 (old orientation): rad = h @ w3.T -> packed regs
    uint2 radp[2][6];
    {
        s16x8 A[2][3];
        #pragma unroll
        for (int mf = 0; mf < 2; mf++)
        #pragma unroll
        for (int kt = 0; kt < 3; kt++)
            A[mf][kt] = *(const s16x8*)&h_s[(mbase + mf*16 + lr) * 104 + kt*32 + lg*8];
        f32x4 rad[2][6] = {};
        #pragma unroll
        for (int nt = 0; nt < 6; nt++)
        #pragma unroll
        for (int kt = 0; kt < 3; kt++) {
            s16x8 B = *(const s16x8*)&wp[21504 + (kt*6 + nt) * 512 + l * 8];
            rad[0][nt] = __builtin_amdgcn_mfma_f32_16x16x32_bf16(A[0][kt], B, rad[0][nt], 0, 0, 0);
            rad[1][nt] = __builtin_amdgcn_mfma_f32_16x16x32_bf16(A[1][kt], B, rad[1][nt], 0, 0, 0);
        }
        #pragma unroll
        for (int mf = 0; mf < 2; mf++)
        #pragma unroll
        for (int nt = 0; nt < 6; nt++)
            radp[mf][nt] = pack4(rad[mf][nt][0], rad[mf][nt][1], rad[mf][nt][2], rad[mf][nt][3]);
    }

    __syncthreads();   // SYNC#2: all row-major reads of h done -> overlay allowed

    // ---- rad -> B-fragment-order stash (overlays h_s[0 .. 12288 u16))
    #pragma unroll
    for (int mf = 0; mf < 2; mf++)
    #pragma unroll
    for (int nt = 0; nt < 6; nt++)
        *(uint2*)&h_s[(w*6 + nt) * 512 + ((2*mf + (lg>>1))*16 + lr) * 8 + (lg&1)*4] = radp[mf][nt];

    __syncthreads();   // SYNC#3: rad frags + segid visible

    // ---- segment reduction (unchanged)
    const int nseg = nseg_s;
    if (w == 0) {
        for (int st = 0; st * 16 < nseg; ++st) {
            const int target = st * 16 + lr;
            f32x4 acc[6] = {};
            #pragma unroll
            for (int kt = 0; kt < 4; kt++) {
                uint2 sid8 = *(const uint2*)&segid_s[kt*32 + 8*lg];
                s16x8 af;
                #pragma unroll
                for (int j = 0; j < 8; j++) {
                    unsigned word = (j < 4) ? sid8.x : sid8.y;
                    int sid = (word >> (8 * (j & 3))) & 255;
                    af[j] = (short)((sid == target) ? 0x3F80 : 0);
                }
                #pragma unroll
                for (int nt = 0; nt < 6; nt++) {
                    s16x8 B = *(const s16x8*)&h_s[(kt*6 + nt) * 512 + l * 8];
                    acc[nt] = __builtin_amdgcn_mfma_f32_16x16x32_bf16(af, B, acc[nt], 0, 0, 0);
                }
            }
            #pragma unroll
            for (int nt = 0; nt < 6; nt++)
            #pragma unroll
            for (int j = 0; j < 4; j++) {
                int g = st*16 + 4*lg + j;
                if (g < nseg) {
                    int node = segnode_s[g];
                    if (node >= 0)
                        unsafeAtomicAdd(&A_a[node*96 + nt*16 + lr], acc[nt][j]);
                }
            }
        }
    } else {
        const int c = w - 1;
        const int scb = 12288 + (w - 1) * 1536;
        for (int st = 0; st * 16 < nseg; ++st) {
            const int target = st * 16 + lr;
            f32x4 acc6[6] = {};
            #pragma unroll
            for (int kt = 0; kt < 4; kt++) {
                uint2 sid8 = *(const uint2*)&segid_s[kt*32 + 8*lg];
                s16x8 rv8 = *(const s16x8*)&rvb_s[c*128 + kt*32 + 8*lg];
                s16x8 af;
                #pragma unroll
                for (int j = 0; j < 8; j++) {
                    unsigned word = (j < 4) ? sid8.x : sid8.y;
                    int sid = (word >> (8 * (j & 3))) & 255;
                    af[j] = (sid == target) ? rv8[j] : (short)0;
                }
                #pragma unroll
                for (int nt = 0; nt < 6; nt++) {
                    s16x8 B = *(const s16x8*)&h_s[(kt*6 + nt) * 512 + l * 8];
                    acc6[nt] = __builtin_amdgcn_mfma_f32_16x16x32_bf16(af, B, acc6[nt], 0, 0, 0);
                }
            }
            #pragma unroll
            for (int nt = 0; nt < 6; nt++) {
                int ktf = nt >> 1;
                int lane2 = ((nt & 1) * 2 + (lr >> 3)) * 16 + 4*lg;
                int a0 = scb + ktf*512 + lane2*8 + (lr & 7);
                h_s[a0]      = f2bf(acc6[nt][0]);
                h_s[a0 + 8]  = f2bf(acc6[nt][1]);
                h_s[a0 + 16] = f2bf(acc6[nt][2]);
                h_s[a0 + 24] = f2bf(acc6[nt][3]);
            }
            s16x8 As[3];
            #pragma unroll
            for (int ktf = 0; ktf < 3; ktf++)
                As[ktf] = *(const s16x8*)&h_s[scb + ktf*512 + l*8];
            f32x4 acc2[4] = {};
            #pragma unroll
            for (int vt = 0; vt < 4; vt++)
            #pragma unroll
            for (int ktf = 0; ktf < 3; ktf++) {
                s16x8 B = *(const s16x8*)&wp[30720 + (ktf*4 + vt) * 512 + l * 8];
                acc2[vt] = __builtin_amdgcn_mfma_f32_16x16x32_bf16(As[ktf], B, acc2[vt], 0, 0, 0);
            }
            #pragma unroll
            for (int vt = 0; vt < 4; vt++)
            #pragma unroll
            for (int j = 0; j < 4; j++) {
                int g = st*16 + 4*lg + j;
                if (g < nseg) {
                    int node = segnode_s[g];
                    if (node >= 0)
                        unsafeAtomicAdd(&Ov[node*192 + (vt*16 + lr)*3 + c], acc2[vt][j]);
                }
            }
        }
    }
}

extern "C" void kernel_launch(void* const* d_in, const int* in_sizes, int n_in,
                              void* d_out, int out_size, void* d_ws, size_t ws_size,
                              hipStream_t stream)
{
    const float* r_ij = (const float*)d_in[0];
    const float* w0   = (const float*)d_in[1];
    const float* b0   = (const float*)d_in[2];
    const float* w1   = (const float*)d_in[3];
    const float* b1   = (const float*)d_in[4];
    const float* w2   = (const float*)d_in[5];
    const float* b2   = (const float*)d_in[6];
    const float* w3   = (const float*)d_in[7];
    const float* wv   = (const float*)d_in[8];
    const int*   src  = (const int*)d_in[9];
    const int E = in_sizes[0] / 3;
    const int N = out_size / 288;
    float* A_a = (float*)d_out;
    float* Ov  = A_a + (size_t)N * 96;

    char* wsb = (char*)d_ws;
    unsigned short* wp = (unsigned short*)wsb;                  // 73728 B
    size_t off = 73728;
    int* counts = (int*)(wsb + off);  off += (((size_t)N*4 + 127) & ~127ull);
    int* cursor = (int*)(wsb + off);  off += (((size_t)N*4 + 127) & ~127ull);
    int* bsum   = (int*)(wsb + off);  off += 1024;
    size_t need_rsrt = off + (size_t)E * 16;
    int use_rsrt = (need_rsrt <= ws_size) ? 1 : 0;
    float4* rsrt = (float4*)(wsb + off);
    int* order   = (int*)(wsb + off);
    int* srcs    = (int*)(wsb + off + (((size_t)E*4 + 127) & ~127ull));

    const int nb = (N + 2047) / 2048;
    const long nz = (long)out_size / 4;     // out_size = 288*N, divisible by 4

    pack_weights_k<<<(PACK_TOT + 255) / 256, 256, 0, stream>>>(w0, w1, w2, w3, wv, wp,
                                                               counts, N);
    hist_k<<<(E + 255) / 256, 256, 0, stream>>>(src, counts, (float4*)d_out, nz, E);
    scan1_k<<<nb, 256, 0, stream>>>(counts, cursor, bsum, N);
    scatter_k<<<(E + 255) / 256, 256, 0, stream>>>(src, r_ij, bsum, cursor,
                                                   order, srcs, rsrt, use_rsrt, nb, E);
    edge_kernel<<<(E + 127) / 128, 256, 0, stream>>>(r_ij, order, srcs, rsrt, use_rsrt,
                                                     wp, b0, b1, b2, A_a, Ov, E);
}

// Round 14
// 227.379 us; speedup vs baseline: 1.2068x; 1.0467x over previous
//
#include <hip/hip_runtime.h>
#include <math.h>

typedef float f32x4 __attribute__((ext_vector_type(4)));
typedef short s16x8 __attribute__((ext_vector_type(8)));

__device__ __forceinline__ unsigned short f2bf(float f) {
    unsigned u = __builtin_bit_cast(unsigned, f);
    u += 0x7fffu + ((u >> 16) & 1u);
    return (unsigned short)(u >> 16);
}

// Pack 4 f32 -> 4 bf16 (round-half-up) via v_perm_b32 (builtin, no asm).
__device__ __forceinline__ uint2 pack4(float q0, float q1, float q2, float q3) {
    unsigned u0 = __builtin_bit_cast(unsigned, q0) + 0x8000u;
    unsigned u1 = __builtin_bit_cast(unsigned, q1) + 0x8000u;
    unsigned u2 = __builtin_bit_cast(unsigned, q2) + 0x8000u;
    unsigned u3 = __builtin_bit_cast(unsigned, q3) + 0x8000u;
    uint2 r;
    r.x = __builtin_amdgcn_perm(u1, u0, 0x07060302);
    r.y = __builtin_amdgcn_perm(u3, u2, 0x07060302);
    return r;
}

// Bijective XCD-chunking swizzle (kept; harmless).
__device__ __forceinline__ int xcd_swizzle(int b, int nwg) {
    int q = nwg >> 3, r = nwg & 7;
    int xcd = b & 7, slot = b >> 3;
    int base = (xcd < r) ? xcd * (q + 1) : r * (q + 1) + (xcd - r) * q;
    return base + slot;
}

// ---------------- weight packing (+ fused counts zeroing) ----------------
// Frag (kt,nt): lane l elem j holds W[16nt+(l&15)][32kt+8*(l>>4)+j].
#define PACK_TOT 36864

__global__ __launch_bounds__(256) void pack_weights_k(
    const float* __restrict__ w0, const float* __restrict__ w1,
    const float* __restrict__ w2, const float* __restrict__ w3,
    const float* __restrict__ wv, unsigned short* __restrict__ dst,
    int* __restrict__ counts, int N)
{
    int idx = blockIdx.x * 256 + threadIdx.x;
    int stride = gridDim.x * 256;
    for (int i = idx; i < N; i += stride) counts[i] = 0;   // replaces memset(counts)
    if (idx >= PACK_TOT) return;
    const float* W; int inF, ntiles, off;
    if (idx < 3072)       { W = w0; inF = 8;  ntiles = 6; off = 0; }
    else if (idx < 12288) { W = w1; inF = 96; ntiles = 6; off = 3072; }
    else if (idx < 21504) { W = w2; inF = 96; ntiles = 6; off = 12288; }
    else if (idx < 30720) { W = w3; inF = 96; ntiles = 6; off = 21504; }
    else                  { W = wv; inF = 96; ntiles = 4; off = 30720; }
    int r  = idx - off;
    int fi = r >> 9;
    int wi = r & 511;
    int l = wi >> 3, j = wi & 7;
    int kt = fi / ntiles, nt = fi - kt * ntiles;
    int n = nt * 16 + (l & 15);
    int k = kt * 32 + ((l >> 4) << 3) + j;
    float v = (k < inF) ? W[n * inF + k] : 0.0f;
    dst[idx] = f2bf(v);
}

// ---------------- CSR build (+ fused d_out zeroing) ----------------
__global__ __launch_bounds__(256) void hist_k(const int* __restrict__ src,
                                              int* __restrict__ counts,
                                              float4* __restrict__ dz, long nz,
                                              int E)
{
    long tid = (long)blockIdx.x * 256 + threadIdx.x;
    long stride = (long)gridDim.x * 256;
    float4 z4 = make_float4(0.f, 0.f, 0.f, 0.f);
    for (long i = tid; i < nz; i += stride) dz[i] = z4;     // replaces memset(d_out)
    int e = blockIdx.x * 256 + threadIdx.x;
    if (e < E) atomicAdd(&counts[src[e]], 1);
}

__global__ __launch_bounds__(256) void scan1_k(const int* __restrict__ counts,
                                               int* __restrict__ cursor,
                                               int* __restrict__ bsum, int N)
{
    __shared__ int wsum_s[4];
    int b = blockIdx.x, t = threadIdx.x, lane = t & 63, wid = t >> 6;
    int i0 = b * 2048 + t * 8;
    int v[8]; int s = 0;
    #pragma unroll
    for (int j = 0; j < 8; j++) { int i = i0 + j; v[j] = (i < N) ? counts[i] : 0; s += v[j]; }
    int inc = s;
    #pragma unroll
    for (int d = 1; d < 64; d <<= 1) { int o = __shfl_up(inc, d, 64); if (lane >= d) inc += o; }
    if (lane == 63) wsum_s[wid] = inc;
    __syncthreads();
    int wb = 0;
    for (int k = 0; k < wid; k++) wb += wsum_s[k];
    int run = wb + inc - s;
    #pragma unroll
    for (int j = 0; j < 8; j++) { int i = i0 + j; if (i < N) cursor[i] = run; run += v[j]; }
    if (t == 255) bsum[b] = wb + inc;
}

// scatter with inline chunk-total prefix; rsrt written non-temporally
__global__ __launch_bounds__(256) void scatter_k(const int* __restrict__ src,
                                                 const float* __restrict__ r_ij,
                                                 const int* __restrict__ bsum,
                                                 int* __restrict__ cursor,
                                                 int* __restrict__ order,
                                                 int* __restrict__ srcs,
                                                 float4* __restrict__ rsrt,
                                                 int use_rsrt, int nb, int E)
{
    __shared__ int pre_s[256];
    int t = threadIdx.x;
    if (t < 64) {
        int carry = 0;
        for (int base = 0; base < nb; base += 64) {
            int i = base + t;
            int v = (i < nb) ? bsum[i] : 0;
            int inc = v;
            #pragma unroll
            for (int d = 1; d < 64; d <<= 1) {
                int o = __shfl_up(inc, d, 64);
                if (t >= d) inc += o;
            }
            if (i < nb) pre_s[i] = carry + inc - v;
            carry += __shfl(inc, 63);
        }
    }
    __syncthreads();
    int e = blockIdx.x * 256 + t;
    if (e < E) {
        int s = src[e];
        int p = pre_s[s >> 11] + atomicAdd(&cursor[s], 1);
        if (use_rsrt) {
            f32x4 v4 = {r_ij[3*e], r_ij[3*e+1], r_ij[3*e+2], __int_as_float(s)};
            __builtin_nontemporal_store(v4, (f32x4*)&rsrt[p]);
        } else {
            order[p] = e;
            srcs[p] = s;
        }
    }
}

// ---------------- fused edge kernel ----------------
// r13 body + interior-segment plain stores: a segment that is neither first
// nor last in the block owns ALL edges of its node (sorted order), so no
// other block writes that node -> plain NT store (full feature coverage)
// instead of atomicAdd. Only ~2 boundary segs/block stay atomic.
__global__ __launch_bounds__(256, 3) void edge_kernel(
    const float* __restrict__ r_ij,
    const int* __restrict__ order, const int* __restrict__ srcs,
    const float4* __restrict__ rsrt, int use_rsrt,
    const unsigned short* __restrict__ wp,
    const float* __restrict__ b0, const float* __restrict__ b1, const float* __restrict__ b2,
    float* __restrict__ A_a, float* __restrict__ Ov, int E)
{
    __shared__ unsigned short h_s[16896];
    __shared__ unsigned short rvb_s[3 * 128];      // bf16 rv, [c][row]
    __shared__ unsigned char  segid_s[128];
    __shared__ int  segnode_s[128];
    __shared__ int  src_s[128];
    __shared__ int  nseg_s;

    const int tid = threadIdx.x;
    const int w  = tid >> 6;
    const int l  = tid & 63;
    const int e0 = xcd_swizzle(blockIdx.x, gridDim.x) * 128;
    const int lr = l & 15;
    const int lg = l >> 4;
    const int mbase = w * 32;

    // ---- stage per-edge scalars
    if (l < 32) {
        const int ml = mbase + l;
        const int pos = e0 + ml;
        float x = 0.f, y = 0.f, z = 0.f; int s = -1;
        if (pos < E) {
            if (use_rsrt) {
                f32x4 t4 = __builtin_nontemporal_load((const f32x4*)&rsrt[pos]);
                x = t4[0]; y = t4[1]; z = t4[2]; s = __float_as_int(t4[3]);
            } else {
                int e = order[pos];
                s = srcs[pos];
                x = r_ij[3*e]; y = r_ij[3*e+1]; z = r_ij[3*e+2];
            }
        }
        float r = sqrtf(x*x + y*y + z*z);
        float u = r * 4.0f;               // r * 8/R0, R0=2
        s16x8 ev;
        #pragma unroll
        for (int k = 0; k < 8; k++) {
            float t = fmaxf(1.0f - fabsf(u - (float)k), 0.0f);
            ev[k] = (short)f2bf((s >= 0) ? t : 0.0f);
        }
        *(s16x8*)&h_s[ml * 104 + 96] = ev;     // enc into pad cols
        float nn = 3.5f * r;
        float sc = (s >= 0) ? (3.5f * tanhf(nn) / fmaxf(nn, 1e-12f)) : 0.0f;
        rvb_s[0*128 + ml] = f2bf(x * sc);
        rvb_s[1*128 + ml] = f2bf(y * sc);
        rvb_s[2*128 + ml] = f2bf(z * sc);
        src_s[ml] = s;
    }
    __syncthreads();   // SYNC#1: src_s/enc visible

    // ---- wave 0: build segid / segnode / nseg (ballot-based prefix)
    if (w == 0) {
        int i = l;
        int sA = src_s[i];
        bool fA = (i == 0) || (sA != src_s[i - 1]);
        unsigned long long mA = __ballot(fA);
        unsigned long long maskA = (~0ull) >> (63 - i);
        int incA = (int)__popcll(mA & maskA);
        segid_s[i] = (unsigned char)(incA - 1);
        if (fA) segnode_s[incA - 1] = sA;
        int totA = (int)__popcll(mA);
        int jrow = 64 + i;
        int sB = src_s[jrow];
        bool fB = (sB != src_s[jrow - 1]);
        unsigned long long mB = __ballot(fB);
        int incB = (int)__popcll(mB & maskA);
        segid_s[jrow] = (unsigned char)(totA + incB - 1);
        if (fB) segnode_s[totA + incB - 1] = sB;
        if (i == 63) nseg_s = totA + (int)__popcll(mB);
    }

    // ---- biases as float4 per (nt, lg): feat = nt*16 + lg*4 + jj (swapped D)
    f32x4 b0v4[6], b1v4[6], b2v4[6];
    #pragma unroll
    for (int nt = 0; nt < 6; nt++) {
        float4 t0 = *(const float4*)&b0[nt*16 + lg*4];
        float4 t1 = *(const float4*)&b1[nt*16 + lg*4];
        float4 t2 = *(const float4*)&b2[nt*16 + lg*4];
        b0v4[nt] = (f32x4){t0.x, t0.y, t0.z, t0.w};
        b1v4[nt] = (f32x4){t1.x, t1.y, t1.z, t1.w};
        b2v4[nt] = (f32x4){t2.x, t2.y, t2.z, t2.w};
    }

    // ---- layer 0 (swapped): D[feat][edge] = w0_frag x enc_frag + b0
    {
        s16x8 hb[2];
        #pragma unroll
        for (int mf = 0; mf < 2; mf++) {
            s16x8 a = {0,0,0,0,0,0,0,0};
            if (l < 16) a = *(const s16x8*)&h_s[(mbase + mf*16 + lr) * 104 + 96];
            hb[mf] = a;
        }
        f32x4 acc[2][6];
        #pragma unroll
        for (int nt = 0; nt < 6; nt++) {
            s16x8 Wf = *(const s16x8*)&wp[nt * 512 + l * 8];
            acc[0][nt] = __builtin_amdgcn_mfma_f32_16x16x32_bf16(Wf, hb[0], b0v4[nt], 0, 0, 0);
            acc[1][nt] = __builtin_amdgcn_mfma_f32_16x16x32_bf16(Wf, hb[1], b0v4[nt], 0, 0, 0);
        }
        #pragma unroll
        for (int mf = 0; mf < 2; mf++)
        #pragma unroll
        for (int nt = 0; nt < 6; nt++)
            *(uint2*)&h_s[(mbase + mf*16 + lr) * 104 + nt*16 + lg*4] =
                pack4(acc[mf][nt][0], acc[mf][nt][1], acc[mf][nt][2], acc[mf][nt][3]);
    }

    // ---- layers 1,2 (swapped): in-place leaky(W x h + b); b64 epilogue
    #pragma unroll
    for (int li = 0; li < 2; li++) {
        const int poff = 3072 + li * 9216;
        s16x8 A[2][3];
        #pragma unroll
        for (int mf = 0; mf < 2; mf++)
        #pragma unroll
        for (int kt = 0; kt < 3; kt++)
            A[mf][kt] = *(const s16x8*)&h_s[(mbase + mf*16 + lr) * 104 + kt*32 + lg*8];
        f32x4 a2[2][6];
        #pragma unroll
        for (int nt = 0; nt < 6; nt++) {
            f32x4 bi = (li == 0) ? b1v4[nt] : b2v4[nt];
            a2[0][nt] = bi; a2[1][nt] = bi;
        }
        #pragma unroll
        for (int nt = 0; nt < 6; nt++)
        #pragma unroll
        for (int kt = 0; kt < 3; kt++) {
            s16x8 Wf = *(const s16x8*)&wp[poff + (kt*6 + nt) * 512 + l * 8];
            a2[0][nt] = __builtin_amdgcn_mfma_f32_16x16x32_bf16(Wf, A[0][kt], a2[0][nt], 0, 0, 0);
            a2[1][nt] = __builtin_amdgcn_mfma_f32_16x16x32_bf16(Wf, A[1][kt], a2[1][nt], 0, 0, 0);
        }
        #pragma unroll
        for (int mf = 0; mf < 2; mf++)
        #pragma unroll
        for (int nt = 0; nt < 6; nt++) {
            float q0 = a2[mf][nt][0], q1 = a2[mf][nt][1];
            float q2 = a2[mf][nt][2], q3 = a2[mf][nt][3];
            q0 = fmaxf(q0, 0.1f*q0); q1 = fmaxf(q1, 0.1f*q1);
            q2 = fmaxf(q2, 0.1f*q2); q3 = fmaxf(q3, 0.1f*q3);
            *(uint2*)&h_s[(mbase + mf*16 + lr) * 104 + nt*16 + lg*4] = pack4(q0, q1, q2, q3);
        }
    }

    // ---- layer 3 (old orientation): rad = h @ w3.T -> packed regs
    uint2 radp[2][6];
    {
        s16x8 A[2][3];
        #pragma unroll
        for (int mf = 0; mf < 2; mf++)
        #pragma unroll
        for (int kt = 0; kt < 3; kt++)
            A[mf][kt] = *(const s16x8*)&h_s[(mbase + mf*16 + lr) * 104 + kt*32 + lg*8];
        f32x4 rad[2][6] = {};
        #pragma unroll
        for (int nt = 0; nt < 6; nt++)
        #pragma unroll
        for (int kt = 0; kt < 3; kt++) {
            s16x8 B = *(const s16x8*)&wp[21504 + (kt*6 + nt) * 512 + l * 8];
            rad[0][nt] = __builtin_amdgcn_mfma_f32_16x16x32_bf16(A[0][kt], B, rad[0][nt], 0, 0, 0);
            rad[1][nt] = __builtin_amdgcn_mfma_f32_16x16x32_bf16(A[1][kt], B, rad[1][nt], 0, 0, 0);
        }
        #pragma unroll
        for (int mf = 0; mf < 2; mf++)
        #pragma unroll
        for (int nt = 0; nt < 6; nt++)
            radp[mf][nt] = pack4(rad[mf][nt][0], rad[mf][nt][1], rad[mf][nt][2], rad[mf][nt][3]);
    }

    __syncthreads();   // SYNC#2: all row-major reads of h done -> overlay allowed

    // ---- rad -> B-fragment-order stash (overlays h_s[0 .. 12288 u16))
    #pragma unroll
    for (int mf = 0; mf < 2; mf++)
    #pragma unroll
    for (int nt = 0; nt < 6; nt++)
        *(uint2*)&h_s[(w*6 + nt) * 512 + ((2*mf + (lg>>1))*16 + lr) * 8 + (lg&1)*4] = radp[mf][nt];

    __syncthreads();   // SYNC#3: rad frags + segid visible

    // ---- segment reduction (interior segs: plain NT store; boundary: atomic)
    const int nseg = nseg_s;
    if (w == 0) {
        for (int st = 0; st * 16 < nseg; ++st) {
            const int target = st * 16 + lr;
            f32x4 acc[6] = {};
            #pragma unroll
            for (int kt = 0; kt < 4; kt++) {
                uint2 sid8 = *(const uint2*)&segid_s[kt*32 + 8*lg];
                s16x8 af;
                #pragma unroll
                for (int j = 0; j < 8; j++) {
                    unsigned word = (j < 4) ? sid8.x : sid8.y;
                    int sid = (word >> (8 * (j & 3))) & 255;
                    af[j] = (short)((sid == target) ? 0x3F80 : 0);
                }
                #pragma unroll
                for (int nt = 0; nt < 6; nt++) {
                    s16x8 B = *(const s16x8*)&h_s[(kt*6 + nt) * 512 + l * 8];
                    acc[nt] = __builtin_amdgcn_mfma_f32_16x16x32_bf16(af, B, acc[nt], 0, 0, 0);
                }
            }
            #pragma unroll
            for (int nt = 0; nt < 6; nt++)
            #pragma unroll
            for (int j = 0; j < 4; j++) {
                int g = st*16 + 4*lg + j;
                if (g < nseg) {
                    int node = segnode_s[g];
                    if (node >= 0) {
                        float* p = &A_a[node*96 + nt*16 + lr];
                        if (g == 0 || g == nseg - 1) unsafeAtomicAdd(p, acc[nt][j]);
                        else __builtin_nontemporal_store(acc[nt][j], p);
                    }
                }
            }
        }
    } else {
        const int c = w - 1;
        const int scb = 12288 + (w - 1) * 1536;
        for (int st = 0; st * 16 < nseg; ++st) {
            const int target = st * 16 + lr;
            f32x4 acc6[6] = {};
            #pragma unroll
            for (int kt = 0; kt < 4; kt++) {
                uint2 sid8 = *(const uint2*)&segid_s[kt*32 + 8*lg];
                s16x8 rv8 = *(const s16x8*)&rvb_s[c*128 + kt*32 + 8*lg];
                s16x8 af;
                #pragma unroll
                for (int j = 0; j < 8; j++) {
                    unsigned word = (j < 4) ? sid8.x : sid8.y;
                    int sid = (word >> (8 * (j & 3))) & 255;
                    af[j] = (sid == target) ? rv8[j] : (short)0;
                }
                #pragma unroll
                for (int nt = 0; nt < 6; nt++) {
                    s16x8 B = *(const s16x8*)&h_s[(kt*6 + nt) * 512 + l * 8];
                    acc6[nt] = __builtin_amdgcn_mfma_f32_16x16x32_bf16(af, B, acc6[nt], 0, 0, 0);
                }
            }
            #pragma unroll
            for (int nt = 0; nt < 6; nt++) {
                int ktf = nt >> 1;
                int lane2 = ((nt & 1) * 2 + (lr >> 3)) * 16 + 4*lg;
                int a0 = scb + ktf*512 + lane2*8 + (lr & 7);
                h_s[a0]      = f2bf(acc6[nt][0]);
                h_s[a0 + 8]  = f2bf(acc6[nt][1]);
                h_s[a0 + 16] = f2bf(acc6[nt][2]);
                h_s[a0 + 24] = f2bf(acc6[nt][3]);
            }
            s16x8 As[3];
            #pragma unroll
            for (int ktf = 0; ktf < 3; ktf++)
                As[ktf] = *(const s16x8*)&h_s[scb + ktf*512 + l*8];
            f32x4 acc2[4] = {};
            #pragma unroll
            for (int vt = 0; vt < 4; vt++)
            #pragma unroll
            for (int ktf = 0; ktf < 3; ktf++) {
                s16x8 B = *(const s16x8*)&wp[30720 + (ktf*4 + vt) * 512 + l * 8];
                acc2[vt] = __builtin_amdgcn_mfma_f32_16x16x32_bf16(As[ktf], B, acc2[vt], 0, 0, 0);
            }
            #pragma unroll
            for (int vt = 0; vt < 4; vt++)
            #pragma unroll
            for (int j = 0; j < 4; j++) {
                int g = st*16 + 4*lg + j;
                if (g < nseg) {
                    int node = segnode_s[g];
                    if (node >= 0) {
                        float* p = &Ov[node*192 + (vt*16 + lr)*3 + c];
                        if (g == 0 || g == nseg - 1) unsafeAtomicAdd(p, acc2[vt][j]);
                        else __builtin_nontemporal_store(acc2[vt][j], p);
                    }
                }
            }
        }
    }
}

extern "C" void kernel_launch(void* const* d_in, const int* in_sizes, int n_in,
                              void* d_out, int out_size, void* d_ws, size_t ws_size,
                              hipStream_t stream)
{
    const float* r_ij = (const float*)d_in[0];
    const float* w0   = (const float*)d_in[1];
    const float* b0   = (const float*)d_in[2];
    const float* w1   = (const float*)d_in[3];
    const float* b1   = (const float*)d_in[4];
    const float* w2   = (const float*)d_in[5];
    const float* b2   = (const float*)d_in[6];
    const float* w3   = (const float*)d_in[7];
    const float* wv   = (const float*)d_in[8];
    const int*   src  = (const int*)d_in[9];
    const int E = in_sizes[0] / 3;
    const int N = out_size / 288;
    float* A_a = (float*)d_out;
    float* Ov  = A_a + (size_t)N * 96;

    char* wsb = (char*)d_ws;
    unsigned short* wp = (unsigned short*)wsb;                  // 73728 B
    size_t off = 73728;
    int* counts = (int*)(wsb + off);  off += (((size_t)N*4 + 127) & ~127ull);
    int* cursor = (int*)(wsb + off);  off += (((size_t)N*4 + 127) & ~127ull);
    int* bsum   = (int*)(wsb + off);  off += 1024;
    size_t need_rsrt = off + (size_t)E * 16;
    int use_rsrt = (need_rsrt <= ws_size) ? 1 : 0;
    float4* rsrt = (float4*)(wsb + off);
    int* order   = (int*)(wsb + off);
    int* srcs    = (int*)(wsb + off + (((size_t)E*4 + 127) & ~127ull));

    const int nb = (N + 2047) / 2048;
    const long nz = (long)out_size / 4;     // out_size = 288*N, divisible by 4

    pack_weights_k<<<(PACK_TOT + 255) / 256, 256, 0, stream>>>(w0, w1, w2, w3, wv, wp,
                                                               counts, N);
    hist_k<<<(E + 255) / 256, 256, 0, stream>>>(src, counts, (float4*)d_out, nz, E);
    scan1_k<<<nb, 256, 0, stream>>>(counts, cursor, bsum, N);
    scatter_k<<<(E + 255) / 256, 256, 0, stream>>>(src, r_ij, bsum, cursor,
                                                   order, srcs, rsrt, use_rsrt, nb, E);
    edge_kernel<<<(E + 127) / 128, 256, 0, stream>>>(r_ij, order, srcs, rsrt, use_rsrt,
                                                     wp, b0, b1, b2, A_a, Ov, E);
}